// Round 2
// baseline (46114.761 us; speedup 1.0000x reference)
//
#include <hip/hip_runtime.h>

#define HF 22
#define SLOPE 0.01f
#define EPS 1e-5f
#define NB 512
#define NT 256
#define RPT 8
#define GSZ (NB*NT)

// LDS: 18401 floats = 73.6 KB -> 2 blocks/CU (160KB), matches launch_bounds(256,2)
struct SM {
  float ovl[16640];          // proj: x tile [256][65] ; after: [0..967] W1 double-buf, [968..1451] W2
  float wp[1408];            // Wp (proj only)
  float red[4][2 * HF];      // block stats reduce
  float a1[HF], c1[HF], a2[HF], c2[HF];
  float b1[2][HF], b2[HF];
  float wo[HF];
  float bo_s;
};

__device__ __forceinline__ float leakyf(float u) { return u > 0.f ? u : SLOPE * u; }

// device-scope spin barrier; safe because all NB blocks are co-resident by construction
__device__ __forceinline__ void gridbar(int* bar) {
  __syncthreads();
  if (threadIdx.x == 0) {
    __hip_atomic_fetch_add(bar, 1, __ATOMIC_ACQ_REL, __HIP_MEMORY_SCOPE_AGENT);
    while (__hip_atomic_load(bar, __ATOMIC_ACQUIRE, __HIP_MEMORY_SCOPE_AGENT) < (int)gridDim.x) {
      __builtin_amdgcn_s_sleep(4);
    }
  }
  __syncthreads();
}

__device__ __forceinline__ void reduce_stats(SM* sm, const float* s, const float* q, float* accStage) {
  int lane = threadIdx.x & 63, w = threadIdx.x >> 6;
#pragma unroll
  for (int j = 0; j < HF; j++) {
    float a = s[j], b = q[j];
#pragma unroll
    for (int o = 32; o; o >>= 1) { a += __shfl_xor(a, o); b += __shfl_xor(b, o); }
    if (lane == 0) { sm->red[w][j] = a; sm->red[w][HF + j] = b; }
  }
  __syncthreads();
  if (threadIdx.x < 2 * HF) {
    float v = sm->red[0][threadIdx.x] + sm->red[1][threadIdx.x]
            + sm->red[2][threadIdx.x] + sm->red[3][threadIdx.x];
    atomicAdd(&accStage[threadIdx.x], v);
  }
}

__device__ __forceinline__ void coeffs(const float* accStage, const float* g, const float* be,
                                       float* sa, float* sc, float invN) {
  int t = threadIdx.x;
  if (t < HF) {
    float su = __hip_atomic_load(&accStage[t], __ATOMIC_ACQUIRE, __HIP_MEMORY_SCOPE_AGENT);
    float sq = __hip_atomic_load(&accStage[HF + t], __ATOMIC_ACQUIRE, __HIP_MEMORY_SCOPE_AGENT);
    float mu = su * invN;
    float var = sq * invN - mu * mu;
    float a = g[t] * rsqrtf(var + EPS);
    sa[t] = a;
    sc[t] = be[t] - a * mu;
  }
}

__device__ __forceinline__ void stage(float* dst, const float* src, int n) {
  for (int i = threadIdx.x; i < n; i += NT) dst[i] = src[i];
}

__global__ void __launch_bounds__(NT, 2) fused_kernel(
    const float* __restrict__ x,
    const float* __restrict__ Wp, const float* __restrict__ bp,
    const float* __restrict__ g0, const float* __restrict__ be0,
    const float* __restrict__ W1s, const float* __restrict__ b1s,
    const float* __restrict__ g1s, const float* __restrict__ be1s,
    const float* __restrict__ W2s, const float* __restrict__ b2s,
    const float* __restrict__ g2s, const float* __restrict__ be2s,
    const float* __restrict__ Wo, const float* __restrict__ bo,
    float* __restrict__ acc, int* __restrict__ bars,
    float* __restrict__ out, int N) {
  __shared__ SM sm;
  const int tid = threadIdx.x;
  const int gid = blockIdx.x * NT + tid;
  const float invN = 1.0f / (float)N;

  float h[RPT][HF];   // persistent activation carry: 8 rows/thread, registers only
  float s[HF], q[HF];

  // ---------------- projection: z0 = Wp@x + bp  (into h), stats -> stage 0
  stage(sm.wp, Wp, 1408);
  if (tid < HF) sm.b2[tid] = bp[tid];
#pragma unroll
  for (int j = 0; j < HF; j++) { s[j] = 0.f; q[j] = 0.f; }

  const float4* x4 = (const float4*)x;
#pragma unroll
  for (int r = 0; r < RPT; r++) {
    __syncthreads();  // protects tile (and Wp/bp stage on r=0)
    size_t base4 = ((size_t)r * GSZ + (size_t)blockIdx.x * NT) * 16;
    for (int c = tid; c < NT * 16; c += NT) {      // coalesced float4 loads of 256 rows
      float4 v = x4[base4 + c];
      int row = c >> 4, col = (c & 15) * 4;
      float* p = &sm.ovl[row * 65 + col];          // pad 65: conflict-free
      p[0] = v.x; p[1] = v.y; p[2] = v.z; p[3] = v.w;
    }
    __syncthreads();
#pragma unroll
    for (int j = 0; j < HF; j++) h[r][j] = sm.b2[j];
    for (int d = 0; d < 64; d++) {
      float xv = sm.ovl[tid * 65 + d];
#pragma unroll
      for (int j = 0; j < HF; j++) h[r][j] += sm.wp[j * 64 + d] * xv;
    }
#pragma unroll
    for (int j = 0; j < HF; j++) { s[j] += h[r][j]; q[j] += h[r][j] * h[r][j]; }
  }
  reduce_stats(&sm, s, q, acc + 0);
  gridbar(bars + 0);

  // ---------------- bn0 apply (in place) + z1_0 stats -> stage 1
  stage(sm.ovl, W1s, 484);                 // W1 layer 0 -> dbuf slot 0
  if (tid < HF) sm.b1[0][tid] = b1s[tid];
  coeffs(acc + 0, g0, be0, sm.a2, sm.c2, invN);
  __syncthreads();
#pragma unroll
  for (int j = 0; j < HF; j++) { s[j] = 0.f; q[j] = 0.f; }
#pragma unroll
  for (int r = 0; r < RPT; r++) {
#pragma unroll
    for (int j = 0; j < HF; j++) h[r][j] = sm.a2[j] * h[r][j] + sm.c2[j];
#pragma unroll
    for (int j = 0; j < HF; j++) {
      float z = sm.b1[0][j];
#pragma unroll
      for (int m = 0; m < HF; m++) z += sm.ovl[j * HF + m] * h[r][m];
      s[j] += z; q[j] += z * z;
    }
  }
  reduce_stats(&sm, s, q, acc + 1 * 44);
  gridbar(bars + 1);

  // ---------------- 16 residual blocks, 2 barriers each
#pragma unroll 1
  for (int k = 0; k < 16; k++) {
    float* sW1  = sm.ovl + (k & 1) * 484;
    float* sW1n = sm.ovl + ((k + 1) & 1) * 484;
    float* sW2  = sm.ovl + 968;
    const float* sb1 = sm.b1[k & 1];

    // ---- P2: recompute z1 -> t ; z2 = W2@t + b2 ; stats(z2)
    stage(sW2, W2s + k * 484, 484);
    if (tid < HF) sm.b2[tid] = b2s[k * HF + tid];
    coeffs(acc + (2 * k + 1) * 44, g1s + k * HF, be1s + k * HF, sm.a1, sm.c1, invN);
    __syncthreads();
#pragma unroll
    for (int j = 0; j < HF; j++) { s[j] = 0.f; q[j] = 0.f; }
#pragma unroll
    for (int r = 0; r < RPT; r++) {
      float t[HF];
#pragma unroll
      for (int j = 0; j < HF; j++) {
        float z = sb1[j];
#pragma unroll
        for (int m = 0; m < HF; m++) z += sW1[j * HF + m] * h[r][m];
        t[j] = leakyf(sm.a1[j] * z + sm.c1[j]);
      }
#pragma unroll
      for (int j = 0; j < HF; j++) {
        float z2 = sm.b2[j];
#pragma unroll
        for (int m = 0; m < HF; m++) z2 += sW2[j * HF + m] * t[m];
        s[j] += z2; q[j] += z2 * z2;
      }
    }
    reduce_stats(&sm, s, q, acc + (2 * k + 2) * 44);
    gridbar(bars + 2 + 2 * k);

    // ---- P3: recompute z1,t,z2 ; h = leaky(h + bn2(z2)) ; fused next-layer z1 stats
    if (k < 15) {
      stage(sW1n, W1s + (k + 1) * 484, 484);
      if (tid < HF) sm.b1[(k + 1) & 1][tid] = b1s[(k + 1) * HF + tid];
    } else {
      if (tid < HF) sm.wo[tid] = Wo[tid];
      if (tid == 0) sm.bo_s = bo[0];
    }
    coeffs(acc + (2 * k + 2) * 44, g2s + k * HF, be2s + k * HF, sm.a2, sm.c2, invN);
    __syncthreads();
#pragma unroll
    for (int j = 0; j < HF; j++) { s[j] = 0.f; q[j] = 0.f; }
    const float* sb1n = sm.b1[(k + 1) & 1];
#pragma unroll
    for (int r = 0; r < RPT; r++) {
      float t[HF];
#pragma unroll
      for (int j = 0; j < HF; j++) {
        float z = sb1[j];
#pragma unroll
        for (int m = 0; m < HF; m++) z += sW1[j * HF + m] * h[r][m];
        t[j] = leakyf(sm.a1[j] * z + sm.c1[j]);
      }
#pragma unroll
      for (int j = 0; j < HF; j++) {
        float z2 = sm.b2[j];
#pragma unroll
        for (int m = 0; m < HF; m++) z2 += sW2[j * HF + m] * t[m];
        h[r][j] = leakyf(h[r][j] + sm.a2[j] * z2 + sm.c2[j]);
      }
      if (k < 15) {
#pragma unroll
        for (int j = 0; j < HF; j++) {
          float z = sb1n[j];
#pragma unroll
          for (int m = 0; m < HF; m++) z += sW1n[j * HF + m] * h[r][m];
          s[j] += z; q[j] += z * z;
        }
      }
    }
    if (k < 15) {
      reduce_stats(&sm, s, q, acc + (2 * k + 3) * 44);
      gridbar(bars + 3 + 2 * k);
    }
  }

  // ---------------- output: out = Wo@h + bo   (coalesced)
#pragma unroll
  for (int r = 0; r < RPT; r++) {
    float o = sm.bo_s;
#pragma unroll
    for (int j = 0; j < HF; j++) o += sm.wo[j] * h[r][j];
    out[(size_t)r * GSZ + gid] = o;
  }
}

extern "C" void kernel_launch(void* const* d_in, const int* in_sizes, int n_in,
                              void* d_out, int out_size, void* d_ws, size_t ws_size,
                              hipStream_t stream) {
  const float* x    = (const float*)d_in[0];
  const float* Wp   = (const float*)d_in[1];
  const float* bp   = (const float*)d_in[2];
  const float* g0   = (const float*)d_in[3];
  const float* be0  = (const float*)d_in[4];
  const float* W1s  = (const float*)d_in[5];
  const float* b1s  = (const float*)d_in[6];
  const float* g1s  = (const float*)d_in[7];
  const float* be1s = (const float*)d_in[8];
  const float* W2s  = (const float*)d_in[9];
  const float* b2s  = (const float*)d_in[10];
  const float* g2s  = (const float*)d_in[11];
  const float* be2s = (const float*)d_in[12];
  const float* Wo   = (const float*)d_in[13];
  const float* bo   = (const float*)d_in[14];

  int N = in_sizes[0] / 64;   // 1048576 == NB*NT*RPT

  float* acc = (float*)d_ws;                       // 33 stages x 44 floats
  int*   bars = (int*)((char*)d_ws + 33 * 44 * sizeof(float));

  hipMemsetAsync(d_ws, 0, 33 * 44 * sizeof(float) + 64 * sizeof(int), stream);

  fused_kernel<<<NB, NT, 0, stream>>>(
      x, Wp, bp, g0, be0, W1s, b1s, g1s, be1s, W2s, b2s, g2s, be2s, Wo, bo,
      acc, bars, (float*)d_out, N);
}

// Round 3
// 37910.730 us; speedup vs baseline: 1.2164x; 1.2164x over previous
//
#include <hip/hip_runtime.h>

#define H 22
#define HH 484
#define SLOPE 0.01f
#define EPS 1e-5f
#define NBLK 1024
#define NT 256
#define GSZ (NBLK * NT)

__device__ __forceinline__ float leakyf(float u) { return u > 0.f ? u : SLOPE * u; }

__device__ __forceinline__ void reduce_stats(float red[4][2 * H], const float* s,
                                             const float* q, float* accStage) {
  int lane = threadIdx.x & 63, w = threadIdx.x >> 6;
#pragma unroll
  for (int j = 0; j < H; j++) {
    float a = s[j], b = q[j];
#pragma unroll
    for (int o = 32; o; o >>= 1) { a += __shfl_xor(a, o); b += __shfl_xor(b, o); }
    if (lane == 0) { red[w][j] = a; red[w][H + j] = b; }
  }
  __syncthreads();
  if ((int)threadIdx.x < 2 * H) {
    float v = red[0][threadIdx.x] + red[1][threadIdx.x] +
              red[2][threadIdx.x] + red[3][threadIdx.x];
    atomicAdd(&accStage[threadIdx.x], v);
  }
}

// ---- proj: z0 = Wp@x + bp -> bufH (feature-major), stats(z0) -> acc stage 0
__global__ void __launch_bounds__(NT, 2) proj_kernel(
    const float* __restrict__ x, const float* __restrict__ Wp,
    const float* __restrict__ bp, float* __restrict__ bufH,
    float* __restrict__ acc0, int N) {
  __shared__ float tile[NT * 65];
  __shared__ float wp[1408];
  __shared__ float sb[H];
  __shared__ float red[4][2 * H];
  int tid = threadIdx.x;
  for (int i = tid; i < 1408; i += NT) wp[i] = Wp[i];
  if (tid < H) sb[tid] = bp[tid];

  float s[H], q[H];
#pragma unroll
  for (int j = 0; j < H; j++) { s[j] = 0.f; q[j] = 0.f; }

  const float4* x4 = (const float4*)x;
  for (int it = 0; it < 4; ++it) {  // N / GSZ == 4
    __syncthreads();
    size_t rowbase = (size_t)it * GSZ + (size_t)blockIdx.x * NT;
    size_t base4 = rowbase * 16;
    for (int c = tid; c < NT * 16; c += NT) {
      float4 v = x4[base4 + c];
      float* p = &tile[(c >> 4) * 65 + (c & 15) * 4];
      p[0] = v.x; p[1] = v.y; p[2] = v.z; p[3] = v.w;
    }
    __syncthreads();
    float z[H];
#pragma unroll
    for (int j = 0; j < H; j++) z[j] = sb[j];
    for (int d = 0; d < 64; d++) {
      float xv = tile[tid * 65 + d];
#pragma unroll
      for (int j = 0; j < H; j++) z[j] += wp[j * 64 + d] * xv;
    }
    size_t i = rowbase + tid;
#pragma unroll
    for (int j = 0; j < H; j++) {
      bufH[(size_t)j * N + i] = z[j];
      s[j] += z[j]; q[j] += z[j] * z[j];
    }
  }
  reduce_stats(red, s, q, acc0);
}

// ---- bn0 apply in place + stats of z1_0 (raw W1 h0 + b1)
__global__ void __launch_bounds__(NT, 3) bn0_kernel(
    float* __restrict__ bufH, const float* __restrict__ accIn,
    float* __restrict__ accOut, const float* __restrict__ g0,
    const float* __restrict__ be0, const float* __restrict__ W1,
    const float* __restrict__ b1, int N) {
  __shared__ float sW[HH];
  __shared__ float sa[H], sc[H], sb[H];
  __shared__ float red[4][2 * H];
  int tid = threadIdx.x;
  for (int i = tid; i < HH; i += NT) sW[i] = W1[i];
  if (tid < H) {
    float invN = 1.0f / (float)N;
    float mu = accIn[tid] * invN;
    float var = accIn[H + tid] * invN - mu * mu;
    float a = g0[tid] * rsqrtf(var + EPS);
    sa[tid] = a; sc[tid] = be0[tid] - a * mu; sb[tid] = b1[tid];
  }
  __syncthreads();

  float s[H], q[H];
#pragma unroll
  for (int j = 0; j < H; j++) { s[j] = 0.f; q[j] = 0.f; }

  int NP = N >> 1;
  for (int p = blockIdx.x * NT + tid; p < NP; p += GSZ) {
    float hA[H], hB[H];
#pragma unroll
    for (int j = 0; j < H; j++) {
      float2 v = *(float2*)&bufH[(size_t)j * N + 2 * (size_t)p];
      v.x = sa[j] * v.x + sc[j];
      v.y = sa[j] * v.y + sc[j];
      *(float2*)&bufH[(size_t)j * N + 2 * (size_t)p] = v;
      hA[j] = v.x; hB[j] = v.y;
    }
#pragma unroll
    for (int j = 0; j < H; j++) {
      float zA = sb[j], zB = sb[j];
#pragma unroll
      for (int m = 0; m < H; m++) {
        float w = sW[j * H + m];
        zA += w * hA[m]; zB += w * hB[m];
      }
      s[j] += zA + zB; q[j] += zA * zA + zB * zB;
    }
  }
  reduce_stats(red, s, q, accOut);
}

// ---- P2: t = leaky(W1f h + b1f) ; z2 = W2 t + b2 (raw) ; stats(z2)
__global__ void __launch_bounds__(NT, 3) p2_kernel(
    const float* __restrict__ bufH, const float* __restrict__ accIn,
    float* __restrict__ accOut, const float* __restrict__ g1,
    const float* __restrict__ be1, const float* __restrict__ W1,
    const float* __restrict__ b1, const float* __restrict__ W2,
    const float* __restrict__ b2, int N) {
  __shared__ float sW1f[HH], sW2[HH];
  __shared__ float sa1[H], sb1f[H], sb2[H];
  __shared__ float red[4][2 * H];
  int tid = threadIdx.x;
  for (int i = tid; i < HH; i += NT) sW2[i] = W2[i];
  if (tid < H) {
    float invN = 1.0f / (float)N;
    float mu = accIn[tid] * invN;
    float var = accIn[H + tid] * invN - mu * mu;
    float a = g1[tid] * rsqrtf(var + EPS);
    float c = be1[tid] - a * mu;
    sa1[tid] = a; sb1f[tid] = a * b1[tid] + c; sb2[tid] = b2[tid];
  }
  __syncthreads();
  for (int i = tid; i < HH; i += NT) sW1f[i] = sa1[i / H] * W1[i];
  __syncthreads();

  float s[H], q[H];
#pragma unroll
  for (int j = 0; j < H; j++) { s[j] = 0.f; q[j] = 0.f; }

  int NP = N >> 1;
  for (int p = blockIdx.x * NT + tid; p < NP; p += GSZ) {
    float hA[H], hB[H], tA[H], tB[H];
#pragma unroll
    for (int j = 0; j < H; j++) {
      float2 v = *(const float2*)&bufH[(size_t)j * N + 2 * (size_t)p];
      hA[j] = v.x; hB[j] = v.y;
    }
#pragma unroll
    for (int j = 0; j < H; j++) {
      float zA = sb1f[j], zB = sb1f[j];
#pragma unroll
      for (int m = 0; m < H; m++) {
        float w = sW1f[j * H + m];
        zA += w * hA[m]; zB += w * hB[m];
      }
      tA[j] = leakyf(zA); tB[j] = leakyf(zB);
    }
#pragma unroll
    for (int j = 0; j < H; j++) {
      float zA = sb2[j], zB = sb2[j];
#pragma unroll
      for (int m = 0; m < H; m++) {
        float w = sW2[j * H + m];
        zA += w * tA[m]; zB += w * tB[m];
      }
      s[j] += zA + zB; q[j] += zA * zA + zB * zB;
    }
  }
  reduce_stats(red, s, q, accOut);
}

// ---- P3: recompute t,z2 ; h' = leaky(h + a2 z2 + c2) ; write h' ;
//          fused raw next-layer z1 stats (or final output when LAST)
template <int LAST>
__global__ void __launch_bounds__(NT, 3) p3_kernel(
    float* __restrict__ bufH, const float* __restrict__ accZ1,
    const float* __restrict__ accZ2, float* __restrict__ accOut,
    const float* __restrict__ g1, const float* __restrict__ be1,
    const float* __restrict__ g2, const float* __restrict__ be2,
    const float* __restrict__ W1, const float* __restrict__ b1,
    const float* __restrict__ W2, const float* __restrict__ b2,
    const float* __restrict__ W1n, const float* __restrict__ b1n,
    const float* __restrict__ Wo, const float* __restrict__ bo,
    float* __restrict__ out, int N) {
  __shared__ float sW1f[HH], sW2f[HH], sW1n[HH];
  __shared__ float sa1[H], sa2[H], sb1f[H], sb2f[H], sb1n[H], swo[H];
  __shared__ float sbo;
  __shared__ float red[4][2 * H];
  int tid = threadIdx.x;
  if (tid < H) {
    float invN = 1.0f / (float)N;
    float mu1 = accZ1[tid] * invN;
    float v1 = accZ1[H + tid] * invN - mu1 * mu1;
    float a1 = g1[tid] * rsqrtf(v1 + EPS);
    float c1 = be1[tid] - a1 * mu1;
    sa1[tid] = a1; sb1f[tid] = a1 * b1[tid] + c1;
    float mu2 = accZ2[tid] * invN;
    float v2 = accZ2[H + tid] * invN - mu2 * mu2;
    float a2 = g2[tid] * rsqrtf(v2 + EPS);
    float c2 = be2[tid] - a2 * mu2;
    sa2[tid] = a2; sb2f[tid] = a2 * b2[tid] + c2;
    if (!LAST) sb1n[tid] = b1n[tid]; else swo[tid] = Wo[tid];
  }
  if (LAST && tid == 0) sbo = bo[0];
  __syncthreads();
  for (int i = tid; i < HH; i += NT) {
    sW1f[i] = sa1[i / H] * W1[i];
    sW2f[i] = sa2[i / H] * W2[i];
    if (!LAST) sW1n[i] = W1n[i];
  }
  __syncthreads();

  float s[H], q[H];
#pragma unroll
  for (int j = 0; j < H; j++) { s[j] = 0.f; q[j] = 0.f; }

  int NP = N >> 1;
  for (int p = blockIdx.x * NT + tid; p < NP; p += GSZ) {
    float hA[H], hB[H], tA[H], tB[H];
#pragma unroll
    for (int j = 0; j < H; j++) {
      float2 v = *(const float2*)&bufH[(size_t)j * N + 2 * (size_t)p];
      hA[j] = v.x; hB[j] = v.y;
    }
#pragma unroll
    for (int j = 0; j < H; j++) {
      float zA = sb1f[j], zB = sb1f[j];
#pragma unroll
      for (int m = 0; m < H; m++) {
        float w = sW1f[j * H + m];
        zA += w * hA[m]; zB += w * hB[m];
      }
      tA[j] = leakyf(zA); tB[j] = leakyf(zB);
    }
#pragma unroll
    for (int j = 0; j < H; j++) {
      float uA = sb2f[j], uB = sb2f[j];
#pragma unroll
      for (int m = 0; m < H; m++) {
        float w = sW2f[j * H + m];
        uA += w * tA[m]; uB += w * tB[m];
      }
      hA[j] = leakyf(hA[j] + uA);
      hB[j] = leakyf(hB[j] + uB);
    }
    if (!LAST) {
#pragma unroll
      for (int j = 0; j < H; j++) {
        *(float2*)&bufH[(size_t)j * N + 2 * (size_t)p] = make_float2(hA[j], hB[j]);
      }
#pragma unroll
      for (int j = 0; j < H; j++) {
        float zA = sb1n[j], zB = sb1n[j];
#pragma unroll
        for (int m = 0; m < H; m++) {
          float w = sW1n[j * H + m];
          zA += w * hA[m]; zB += w * hB[m];
        }
        s[j] += zA + zB; q[j] += zA * zA + zB * zB;
      }
    } else {
      float oA = sbo, oB = sbo;
#pragma unroll
      for (int j = 0; j < H; j++) { oA += swo[j] * hA[j]; oB += swo[j] * hB[j]; }
      *(float2*)&out[2 * (size_t)p] = make_float2(oA, oB);
    }
  }
  if (!LAST) reduce_stats(red, s, q, accOut);
}

extern "C" void kernel_launch(void* const* d_in, const int* in_sizes, int n_in,
                              void* d_out, int out_size, void* d_ws, size_t ws_size,
                              hipStream_t stream) {
  const float* x    = (const float*)d_in[0];
  const float* Wp   = (const float*)d_in[1];
  const float* bp   = (const float*)d_in[2];
  const float* g0   = (const float*)d_in[3];
  const float* be0  = (const float*)d_in[4];
  const float* W1s  = (const float*)d_in[5];
  const float* b1s  = (const float*)d_in[6];
  const float* g1s  = (const float*)d_in[7];
  const float* be1s = (const float*)d_in[8];
  const float* W2s  = (const float*)d_in[9];
  const float* b2s  = (const float*)d_in[10];
  const float* g2s  = (const float*)d_in[11];
  const float* be2s = (const float*)d_in[12];
  const float* Wo   = (const float*)d_in[13];
  const float* bo   = (const float*)d_in[14];

  int N = in_sizes[0] / 64;  // 1048576

  float* bufH = (float*)d_ws;
  float* acc = bufH + (size_t)H * N;  // 33 stages x 44 floats

  hipMemsetAsync(acc, 0, 33 * 2 * H * sizeof(float), stream);

  dim3 grid(NBLK), block(NT);

  proj_kernel<<<grid, block, 0, stream>>>(x, Wp, bp, bufH, acc, N);
  bn0_kernel<<<grid, block, 0, stream>>>(bufH, acc, acc + 44, g0, be0, W1s, b1s, N);

  for (int k = 0; k < 16; k++) {
    p2_kernel<<<grid, block, 0, stream>>>(
        bufH, acc + (2 * k + 1) * 44, acc + (2 * k + 2) * 44,
        g1s + k * H, be1s + k * H, W1s + k * HH, b1s + k * H,
        W2s + k * HH, b2s + k * H, N);
    if (k < 15) {
      p3_kernel<0><<<grid, block, 0, stream>>>(
          bufH, acc + (2 * k + 1) * 44, acc + (2 * k + 2) * 44, acc + (2 * k + 3) * 44,
          g1s + k * H, be1s + k * H, g2s + k * H, be2s + k * H,
          W1s + k * HH, b1s + k * H, W2s + k * HH, b2s + k * H,
          W1s + (k + 1) * HH, b1s + (k + 1) * H, nullptr, nullptr, nullptr, N);
    } else {
      p3_kernel<1><<<grid, block, 0, stream>>>(
          bufH, acc + (2 * k + 1) * 44, acc + (2 * k + 2) * 44, nullptr,
          g1s + k * H, be1s + k * H, g2s + k * H, be2s + k * H,
          W1s + k * HH, b1s + k * H, W2s + k * HH, b2s + k * H,
          W1s + k * HH, b1s + k * H, Wo, bo, (float*)d_out, N);
    }
  }
}

// Round 4
// 29530.414 us; speedup vs baseline: 1.5616x; 1.2838x over previous
//
#include <hip/hip_runtime.h>

#define H 22
#define HH 484
#define SLOPE 0.01f
#define EPS 1e-5f
#define NBLK 1024
#define NT 256
#define GSZ (NBLK * NT)

__device__ __forceinline__ float leakyf(float u) { return u > 0.f ? u : SLOPE * u; }

__device__ __forceinline__ void reduce_stats(float red[4][2 * H], const float* s,
                                             const float* q, float* accStage) {
  int lane = threadIdx.x & 63, w = threadIdx.x >> 6;
#pragma unroll
  for (int j = 0; j < H; j++) {
    float a = s[j], b = q[j];
#pragma unroll
    for (int o = 32; o; o >>= 1) { a += __shfl_xor(a, o); b += __shfl_xor(b, o); }
    if (lane == 0) { red[w][j] = a; red[w][H + j] = b; }
  }
  __syncthreads();
  if ((int)threadIdx.x < 2 * H) {
    float v = red[0][threadIdx.x] + red[1][threadIdx.x] +
              red[2][threadIdx.x] + red[3][threadIdx.x];
    atomicAdd(&accStage[threadIdx.x], v);
  }
}

// ---- proj: z0 = Wp@x + bp -> bufH (feature-major), stats(z0) -> acc stage 0
__global__ void __launch_bounds__(NT) proj_kernel(
    const float* __restrict__ x, const float* __restrict__ Wp,
    const float* __restrict__ bp, float* __restrict__ bufH,
    float* __restrict__ acc0, int N) {
  __shared__ float tile[NT * 65];
  __shared__ float wp[1408];
  __shared__ float sb[H];
  __shared__ float red[4][2 * H];
  int tid = threadIdx.x;
  for (int i = tid; i < 1408; i += NT) wp[i] = Wp[i];
  if (tid < H) sb[tid] = bp[tid];

  float s[H], q[H];
#pragma unroll
  for (int j = 0; j < H; j++) { s[j] = 0.f; q[j] = 0.f; }

  const float4* x4 = (const float4*)x;
  for (int it = 0; it < 4; ++it) {  // N / GSZ == 4
    __syncthreads();
    size_t rowbase = (size_t)it * GSZ + (size_t)blockIdx.x * NT;
    size_t base4 = rowbase * 16;
    for (int c = tid; c < NT * 16; c += NT) {
      float4 v = x4[base4 + c];
      float* p = &tile[(c >> 4) * 65 + (c & 15) * 4];
      p[0] = v.x; p[1] = v.y; p[2] = v.z; p[3] = v.w;
    }
    __syncthreads();
    float z[H];
#pragma unroll
    for (int j = 0; j < H; j++) z[j] = sb[j];
    for (int d = 0; d < 64; d++) {
      float xv = tile[tid * 65 + d];
#pragma unroll
      for (int j = 0; j < H; j++) z[j] += wp[j * 64 + d] * xv;
    }
    size_t i = rowbase + tid;
#pragma unroll
    for (int j = 0; j < H; j++) {
      bufH[(size_t)j * N + i] = z[j];
      s[j] += z[j]; q[j] += z[j] * z[j];
    }
  }
  reduce_stats(red, s, q, acc0);
}

// ---- bn0 apply in place + stats of z1_0 (raw W1 h0 + b1)
__global__ void __launch_bounds__(NT) bn0_kernel(
    float* __restrict__ bufH, const float* __restrict__ accIn,
    float* __restrict__ accOut, const float* __restrict__ g0,
    const float* __restrict__ be0, const float* __restrict__ W1,
    const float* __restrict__ b1, int N) {
  __shared__ float sW[HH];
  __shared__ float sa[H], sc[H], sb[H];
  __shared__ float red[4][2 * H];
  int tid = threadIdx.x;
  for (int i = tid; i < HH; i += NT) sW[i] = W1[i];
  if (tid < H) {
    float invN = 1.0f / (float)N;
    float mu = accIn[tid] * invN;
    float var = accIn[H + tid] * invN - mu * mu;
    float a = g0[tid] * rsqrtf(var + EPS);
    sa[tid] = a; sc[tid] = be0[tid] - a * mu; sb[tid] = b1[tid];
  }
  __syncthreads();

  float s[H], q[H];
#pragma unroll
  for (int j = 0; j < H; j++) { s[j] = 0.f; q[j] = 0.f; }

  for (int i = blockIdx.x * NT + tid; i < N; i += GSZ) {
    float h[H];
#pragma unroll
    for (int j = 0; j < H; j++) {
      float v = bufH[(size_t)j * N + i];
      v = sa[j] * v + sc[j];
      bufH[(size_t)j * N + i] = v;
      h[j] = v;
    }
#pragma unroll
    for (int j = 0; j < H; j++) {
      float z = sb[j];
#pragma unroll
      for (int m = 0; m < H; m++) z += sW[j * H + m] * h[m];
      s[j] += z; q[j] += z * z;
    }
  }
  reduce_stats(red, s, q, accOut);
}

// ---- P2: t = leaky(W1f h + b1f) ; z2 = W2 t + b2 (raw) ; stats(z2)
__global__ void __launch_bounds__(NT) p2_kernel(
    const float* __restrict__ bufH, const float* __restrict__ accIn,
    float* __restrict__ accOut, const float* __restrict__ g1,
    const float* __restrict__ be1, const float* __restrict__ W1,
    const float* __restrict__ b1, const float* __restrict__ W2,
    const float* __restrict__ b2, int N) {
  __shared__ float sW1f[HH], sW2[HH];
  __shared__ float sa1[H], sb1f[H], sb2[H];
  __shared__ float red[4][2 * H];
  int tid = threadIdx.x;
  for (int i = tid; i < HH; i += NT) sW2[i] = W2[i];
  if (tid < H) {
    float invN = 1.0f / (float)N;
    float mu = accIn[tid] * invN;
    float var = accIn[H + tid] * invN - mu * mu;
    float a = g1[tid] * rsqrtf(var + EPS);
    float c = be1[tid] - a * mu;
    sa1[tid] = a; sb1f[tid] = a * b1[tid] + c; sb2[tid] = b2[tid];
  }
  __syncthreads();
  for (int i = tid; i < HH; i += NT) sW1f[i] = sa1[i / H] * W1[i];
  __syncthreads();

  float s[H], q[H];
#pragma unroll
  for (int j = 0; j < H; j++) { s[j] = 0.f; q[j] = 0.f; }

  for (int i = blockIdx.x * NT + tid; i < N; i += GSZ) {
    float h[H], t[H];
#pragma unroll
    for (int j = 0; j < H; j++) h[j] = bufH[(size_t)j * N + i];
#pragma unroll
    for (int j = 0; j < H; j++) {
      float z = sb1f[j];
#pragma unroll
      for (int m = 0; m < H; m++) z += sW1f[j * H + m] * h[m];
      t[j] = leakyf(z);
    }
#pragma unroll
    for (int j = 0; j < H; j++) {
      float z = sb2[j];
#pragma unroll
      for (int m = 0; m < H; m++) z += sW2[j * H + m] * t[m];
      s[j] += z; q[j] += z * z;
    }
  }
  reduce_stats(red, s, q, accOut);
}

// ---- P3: recompute t,z2 ; h' = leaky(h + a2 z2 + c2) ; write h' ;
//          fused raw next-layer z1 stats (or final output when LAST)
template <int LAST>
__global__ void __launch_bounds__(NT) p3_kernel(
    float* __restrict__ bufH, const float* __restrict__ accZ1,
    const float* __restrict__ accZ2, float* __restrict__ accOut,
    const float* __restrict__ g1, const float* __restrict__ be1,
    const float* __restrict__ g2, const float* __restrict__ be2,
    const float* __restrict__ W1, const float* __restrict__ b1,
    const float* __restrict__ W2, const float* __restrict__ b2,
    const float* __restrict__ W1n, const float* __restrict__ b1n,
    const float* __restrict__ Wo, const float* __restrict__ bo,
    float* __restrict__ out, int N) {
  __shared__ float sW1f[HH], sW2f[HH], sW1n[HH];
  __shared__ float sa1[H], sa2[H], sb1f[H], sb2f[H], sb1n[H], swo[H];
  __shared__ float sbo;
  __shared__ float red[4][2 * H];
  int tid = threadIdx.x;
  if (tid < H) {
    float invN = 1.0f / (float)N;
    float mu1 = accZ1[tid] * invN;
    float v1 = accZ1[H + tid] * invN - mu1 * mu1;
    float a1 = g1[tid] * rsqrtf(v1 + EPS);
    float c1 = be1[tid] - a1 * mu1;
    sa1[tid] = a1; sb1f[tid] = a1 * b1[tid] + c1;
    float mu2 = accZ2[tid] * invN;
    float v2 = accZ2[H + tid] * invN - mu2 * mu2;
    float a2 = g2[tid] * rsqrtf(v2 + EPS);
    float c2 = be2[tid] - a2 * mu2;
    sa2[tid] = a2; sb2f[tid] = a2 * b2[tid] + c2;
    if (!LAST) sb1n[tid] = b1n[tid]; else swo[tid] = Wo[tid];
  }
  if (LAST && tid == 0) sbo = bo[0];
  __syncthreads();
  for (int i = tid; i < HH; i += NT) {
    sW1f[i] = sa1[i / H] * W1[i];
    sW2f[i] = sa2[i / H] * W2[i];
    if (!LAST) sW1n[i] = W1n[i];
  }
  __syncthreads();

  float s[H], q[H];
#pragma unroll
  for (int j = 0; j < H; j++) { s[j] = 0.f; q[j] = 0.f; }

  for (int i = blockIdx.x * NT + tid; i < N; i += GSZ) {
    float h[H], t[H];
#pragma unroll
    for (int j = 0; j < H; j++) h[j] = bufH[(size_t)j * N + i];
#pragma unroll
    for (int j = 0; j < H; j++) {
      float z = sb1f[j];
#pragma unroll
      for (int m = 0; m < H; m++) z += sW1f[j * H + m] * h[m];
      t[j] = leakyf(z);
    }
#pragma unroll
    for (int j = 0; j < H; j++) {
      float u = sb2f[j];
#pragma unroll
      for (int m = 0; m < H; m++) u += sW2f[j * H + m] * t[m];
      h[j] = leakyf(h[j] + u);
    }
    if (!LAST) {
#pragma unroll
      for (int j = 0; j < H; j++) bufH[(size_t)j * N + i] = h[j];
#pragma unroll
      for (int j = 0; j < H; j++) {
        float z = sb1n[j];
#pragma unroll
        for (int m = 0; m < H; m++) z += sW1n[j * H + m] * h[m];
        s[j] += z; q[j] += z * z;
      }
    } else {
      float o = sbo;
#pragma unroll
      for (int j = 0; j < H; j++) o += swo[j] * h[j];
      out[i] = o;
    }
  }
  if (!LAST) reduce_stats(red, s, q, accOut);
}

extern "C" void kernel_launch(void* const* d_in, const int* in_sizes, int n_in,
                              void* d_out, int out_size, void* d_ws, size_t ws_size,
                              hipStream_t stream) {
  const float* x    = (const float*)d_in[0];
  const float* Wp   = (const float*)d_in[1];
  const float* bp   = (const float*)d_in[2];
  const float* g0   = (const float*)d_in[3];
  const float* be0  = (const float*)d_in[4];
  const float* W1s  = (const float*)d_in[5];
  const float* b1s  = (const float*)d_in[6];
  const float* g1s  = (const float*)d_in[7];
  const float* be1s = (const float*)d_in[8];
  const float* W2s  = (const float*)d_in[9];
  const float* b2s  = (const float*)d_in[10];
  const float* g2s  = (const float*)d_in[11];
  const float* be2s = (const float*)d_in[12];
  const float* Wo   = (const float*)d_in[13];
  const float* bo   = (const float*)d_in[14];

  int N = in_sizes[0] / 64;  // 1048576

  float* bufH = (float*)d_ws;
  float* acc = bufH + (size_t)H * N;  // 33 stages x 44 floats

  hipMemsetAsync(acc, 0, 33 * 2 * H * sizeof(float), stream);

  dim3 grid(NBLK), block(NT);

  proj_kernel<<<grid, block, 0, stream>>>(x, Wp, bp, bufH, acc, N);
  bn0_kernel<<<grid, block, 0, stream>>>(bufH, acc, acc + 44, g0, be0, W1s, b1s, N);

  for (int k = 0; k < 16; k++) {
    p2_kernel<<<grid, block, 0, stream>>>(
        bufH, acc + (2 * k + 1) * 44, acc + (2 * k + 2) * 44,
        g1s + k * H, be1s + k * H, W1s + k * HH, b1s + k * H,
        W2s + k * HH, b2s + k * H, N);
    if (k < 15) {
      p3_kernel<0><<<grid, block, 0, stream>>>(
          bufH, acc + (2 * k + 1) * 44, acc + (2 * k + 2) * 44, acc + (2 * k + 3) * 44,
          g1s + k * H, be1s + k * H, g2s + k * H, be2s + k * H,
          W1s + k * HH, b1s + k * H, W2s + k * HH, b2s + k * H,
          W1s + (k + 1) * HH, b1s + (k + 1) * H, nullptr, nullptr, nullptr, N);
    } else {
      p3_kernel<1><<<grid, block, 0, stream>>>(
          bufH, acc + (2 * k + 1) * 44, acc + (2 * k + 2) * 44, nullptr,
          g1s + k * H, be1s + k * H, g2s + k * H, be2s + k * H,
          W1s + k * HH, b1s + k * H, W2s + k * HH, b2s + k * H,
          W1s + k * HH, b1s + k * H, Wo, bo, (float*)d_out, N);
    }
  }
}

// Round 5
// 7321.349 us; speedup vs baseline: 6.2987x; 4.0335x over previous
//
#include <hip/hip_runtime.h>

#define H 22
#define HH 484
#define SLOPE 0.01f
#define EPS 1e-5f
#define NBLK 1024
#define NT 256
#define GSZ (NBLK * NT)

// Forbid LICM from hoisting (constant-indexed) LDS weight loads out of the
// streaming loop: without this, all ~968 weight loads get cached in registers
// across iterations -> catastrophic spill (rounds 3/4: 2-5 GB scratch traffic).
#define ANTI_HOIST() asm volatile("" ::: "memory")

__device__ __forceinline__ float leakyf(float u) { return u > 0.f ? u : SLOPE * u; }

__device__ __forceinline__ void reduce_stats(float red[4][2 * H], const float* s,
                                             const float* q, float* accStage) {
  int lane = threadIdx.x & 63, w = threadIdx.x >> 6;
#pragma unroll
  for (int j = 0; j < H; j++) {
    float a = s[j], b = q[j];
#pragma unroll
    for (int o = 32; o; o >>= 1) { a += __shfl_xor(a, o); b += __shfl_xor(b, o); }
    if (lane == 0) { red[w][j] = a; red[w][H + j] = b; }
  }
  __syncthreads();
  if ((int)threadIdx.x < 2 * H) {
    float v = red[0][threadIdx.x] + red[1][threadIdx.x] +
              red[2][threadIdx.x] + red[3][threadIdx.x];
    atomicAdd(&accStage[threadIdx.x], v);
  }
}

// ---- proj: z0 = Wp@x + bp -> bufH (feature-major), stats(z0) -> acc stage 0
__global__ void __launch_bounds__(NT) proj_kernel(
    const float* __restrict__ x, const float* __restrict__ Wp,
    const float* __restrict__ bp, float* __restrict__ bufH,
    float* __restrict__ acc0, int N) {
  __shared__ float tile[NT * 65];
  __shared__ float wp[1408];
  __shared__ float sb[H];
  __shared__ float red[4][2 * H];
  int tid = threadIdx.x;
  for (int i = tid; i < 1408; i += NT) wp[i] = Wp[i];
  if (tid < H) sb[tid] = bp[tid];

  float s[H], q[H];
#pragma unroll
  for (int j = 0; j < H; j++) { s[j] = 0.f; q[j] = 0.f; }

  const float4* x4 = (const float4*)x;
  for (int it = 0; it < 4; ++it) {  // N / GSZ == 4
    ANTI_HOIST();
    __syncthreads();
    size_t rowbase = (size_t)it * GSZ + (size_t)blockIdx.x * NT;
    size_t base4 = rowbase * 16;
    for (int c = tid; c < NT * 16; c += NT) {
      float4 v = x4[base4 + c];
      float* p = &tile[(c >> 4) * 65 + (c & 15) * 4];
      p[0] = v.x; p[1] = v.y; p[2] = v.z; p[3] = v.w;
    }
    __syncthreads();
    float z[H];
#pragma unroll
    for (int j = 0; j < H; j++) z[j] = sb[j];
#pragma unroll 1
    for (int d = 0; d < 64; d++) {
      float xv = tile[tid * 65 + d];
#pragma unroll
      for (int j = 0; j < H; j++) z[j] += wp[j * 64 + d] * xv;
    }
    size_t i = rowbase + tid;
#pragma unroll
    for (int j = 0; j < H; j++) {
      bufH[(size_t)j * N + i] = z[j];
      s[j] += z[j]; q[j] += z[j] * z[j];
    }
  }
  reduce_stats(red, s, q, acc0);
}

// ---- bn0 apply in place + stats of z1_0 (raw W1 h0 + b1)
__global__ void __launch_bounds__(NT) bn0_kernel(
    float* __restrict__ bufH, const float* __restrict__ accIn,
    float* __restrict__ accOut, const float* __restrict__ g0,
    const float* __restrict__ be0, const float* __restrict__ W1,
    const float* __restrict__ b1, int N) {
  __shared__ float sW[HH];
  __shared__ float sa[H], sc[H], sb[H];
  __shared__ float red[4][2 * H];
  int tid = threadIdx.x;
  for (int i = tid; i < HH; i += NT) sW[i] = W1[i];
  if (tid < H) {
    float invN = 1.0f / (float)N;
    float mu = accIn[tid] * invN;
    float var = accIn[H + tid] * invN - mu * mu;
    float a = g0[tid] * rsqrtf(var + EPS);
    sa[tid] = a; sc[tid] = be0[tid] - a * mu; sb[tid] = b1[tid];
  }
  __syncthreads();

  float s[H], q[H];
#pragma unroll
  for (int j = 0; j < H; j++) { s[j] = 0.f; q[j] = 0.f; }

  for (int i = blockIdx.x * NT + tid; i < N; i += GSZ) {
    ANTI_HOIST();
    float h[H];
#pragma unroll
    for (int j = 0; j < H; j++) {
      float v = bufH[(size_t)j * N + i];
      v = sa[j] * v + sc[j];
      bufH[(size_t)j * N + i] = v;
      h[j] = v;
    }
#pragma unroll
    for (int j = 0; j < H; j++) {
      float z = sb[j];
#pragma unroll
      for (int m = 0; m < H; m++) z += sW[j * H + m] * h[m];
      s[j] += z; q[j] += z * z;
    }
  }
  reduce_stats(red, s, q, accOut);
}

// ---- P2: t = leaky(W1f h + b1f) ; z2 = W2 t + b2 (raw) ; stats(z2)
__global__ void __launch_bounds__(NT) p2_kernel(
    const float* __restrict__ bufH, const float* __restrict__ accIn,
    float* __restrict__ accOut, const float* __restrict__ g1,
    const float* __restrict__ be1, const float* __restrict__ W1,
    const float* __restrict__ b1, const float* __restrict__ W2,
    const float* __restrict__ b2, int N) {
  __shared__ float sW1f[HH], sW2[HH];
  __shared__ float sa1[H], sb1f[H], sb2[H];
  __shared__ float red[4][2 * H];
  int tid = threadIdx.x;
  for (int i = tid; i < HH; i += NT) sW2[i] = W2[i];
  if (tid < H) {
    float invN = 1.0f / (float)N;
    float mu = accIn[tid] * invN;
    float var = accIn[H + tid] * invN - mu * mu;
    float a = g1[tid] * rsqrtf(var + EPS);
    float c = be1[tid] - a * mu;
    sa1[tid] = a; sb1f[tid] = a * b1[tid] + c; sb2[tid] = b2[tid];
  }
  __syncthreads();
  for (int i = tid; i < HH; i += NT) sW1f[i] = sa1[i / H] * W1[i];
  __syncthreads();

  float s[H], q[H];
#pragma unroll
  for (int j = 0; j < H; j++) { s[j] = 0.f; q[j] = 0.f; }

  for (int i = blockIdx.x * NT + tid; i < N; i += GSZ) {
    ANTI_HOIST();
    float h[H], t[H];
#pragma unroll
    for (int j = 0; j < H; j++) h[j] = bufH[(size_t)j * N + i];
#pragma unroll
    for (int j = 0; j < H; j++) {
      float z = sb1f[j];
#pragma unroll
      for (int m = 0; m < H; m++) z += sW1f[j * H + m] * h[m];
      t[j] = leakyf(z);
    }
#pragma unroll
    for (int j = 0; j < H; j++) {
      float z = sb2[j];
#pragma unroll
      for (int m = 0; m < H; m++) z += sW2[j * H + m] * t[m];
      s[j] += z; q[j] += z * z;
    }
  }
  reduce_stats(red, s, q, accOut);
}

// ---- P3: recompute t,z2 ; h' = leaky(h + a2 z2 + c2) ; write h' ;
//          fused raw next-layer z1 stats (or final output when LAST)
template <int LAST>
__global__ void __launch_bounds__(NT) p3_kernel(
    float* __restrict__ bufH, const float* __restrict__ accZ1,
    const float* __restrict__ accZ2, float* __restrict__ accOut,
    const float* __restrict__ g1, const float* __restrict__ be1,
    const float* __restrict__ g2, const float* __restrict__ be2,
    const float* __restrict__ W1, const float* __restrict__ b1,
    const float* __restrict__ W2, const float* __restrict__ b2,
    const float* __restrict__ W1n, const float* __restrict__ b1n,
    const float* __restrict__ Wo, const float* __restrict__ bo,
    float* __restrict__ out, int N) {
  __shared__ float sW1f[HH], sW2f[HH], sW1n[HH];
  __shared__ float sa1[H], sa2[H], sb1f[H], sb2f[H], sb1n[H], swo[H];
  __shared__ float sbo;
  __shared__ float red[4][2 * H];
  int tid = threadIdx.x;
  if (tid < H) {
    float invN = 1.0f / (float)N;
    float mu1 = accZ1[tid] * invN;
    float v1 = accZ1[H + tid] * invN - mu1 * mu1;
    float a1 = g1[tid] * rsqrtf(v1 + EPS);
    float c1 = be1[tid] - a1 * mu1;
    sa1[tid] = a1; sb1f[tid] = a1 * b1[tid] + c1;
    float mu2 = accZ2[tid] * invN;
    float v2 = accZ2[H + tid] * invN - mu2 * mu2;
    float a2 = g2[tid] * rsqrtf(v2 + EPS);
    float c2 = be2[tid] - a2 * mu2;
    sa2[tid] = a2; sb2f[tid] = a2 * b2[tid] + c2;
    if (!LAST) sb1n[tid] = b1n[tid]; else swo[tid] = Wo[tid];
  }
  if (LAST && tid == 0) sbo = bo[0];
  __syncthreads();
  for (int i = tid; i < HH; i += NT) {
    sW1f[i] = sa1[i / H] * W1[i];
    sW2f[i] = sa2[i / H] * W2[i];
    if (!LAST) sW1n[i] = W1n[i];
  }
  __syncthreads();

  float s[H], q[H];
#pragma unroll
  for (int j = 0; j < H; j++) { s[j] = 0.f; q[j] = 0.f; }

  for (int i = blockIdx.x * NT + tid; i < N; i += GSZ) {
    ANTI_HOIST();
    float h[H], t[H];
#pragma unroll
    for (int j = 0; j < H; j++) h[j] = bufH[(size_t)j * N + i];
#pragma unroll
    for (int j = 0; j < H; j++) {
      float z = sb1f[j];
#pragma unroll
      for (int m = 0; m < H; m++) z += sW1f[j * H + m] * h[m];
      t[j] = leakyf(z);
    }
#pragma unroll
    for (int j = 0; j < H; j++) {
      float u = sb2f[j];
#pragma unroll
      for (int m = 0; m < H; m++) u += sW2f[j * H + m] * t[m];
      h[j] = leakyf(h[j] + u);
    }
    if (!LAST) {
#pragma unroll
      for (int j = 0; j < H; j++) bufH[(size_t)j * N + i] = h[j];
#pragma unroll
      for (int j = 0; j < H; j++) {
        float z = sb1n[j];
#pragma unroll
        for (int m = 0; m < H; m++) z += sW1n[j * H + m] * h[m];
        s[j] += z; q[j] += z * z;
      }
    } else {
      float o = sbo;
#pragma unroll
      for (int j = 0; j < H; j++) o += swo[j] * h[j];
      out[i] = o;
    }
  }
  if (!LAST) reduce_stats(red, s, q, accOut);
}

extern "C" void kernel_launch(void* const* d_in, const int* in_sizes, int n_in,
                              void* d_out, int out_size, void* d_ws, size_t ws_size,
                              hipStream_t stream) {
  const float* x    = (const float*)d_in[0];
  const float* Wp   = (const float*)d_in[1];
  const float* bp   = (const float*)d_in[2];
  const float* g0   = (const float*)d_in[3];
  const float* be0  = (const float*)d_in[4];
  const float* W1s  = (const float*)d_in[5];
  const float* b1s  = (const float*)d_in[6];
  const float* g1s  = (const float*)d_in[7];
  const float* be1s = (const float*)d_in[8];
  const float* W2s  = (const float*)d_in[9];
  const float* b2s  = (const float*)d_in[10];
  const float* g2s  = (const float*)d_in[11];
  const float* be2s = (const float*)d_in[12];
  const float* Wo   = (const float*)d_in[13];
  const float* bo   = (const float*)d_in[14];

  int N = in_sizes[0] / 64;  // 1048576

  float* bufH = (float*)d_ws;
  float* acc = bufH + (size_t)H * N;  // 33 stages x 44 floats

  hipMemsetAsync(acc, 0, 33 * 2 * H * sizeof(float), stream);

  dim3 grid(NBLK), block(NT);

  proj_kernel<<<grid, block, 0, stream>>>(x, Wp, bp, bufH, acc, N);
  bn0_kernel<<<grid, block, 0, stream>>>(bufH, acc, acc + 44, g0, be0, W1s, b1s, N);

  for (int k = 0; k < 16; k++) {
    p2_kernel<<<grid, block, 0, stream>>>(
        bufH, acc + (2 * k + 1) * 44, acc + (2 * k + 2) * 44,
        g1s + k * H, be1s + k * H, W1s + k * HH, b1s + k * H,
        W2s + k * HH, b2s + k * H, N);
    if (k < 15) {
      p3_kernel<0><<<grid, block, 0, stream>>>(
          bufH, acc + (2 * k + 1) * 44, acc + (2 * k + 2) * 44, acc + (2 * k + 3) * 44,
          g1s + k * H, be1s + k * H, g2s + k * H, be2s + k * H,
          W1s + k * HH, b1s + k * H, W2s + k * HH, b2s + k * H,
          W1s + (k + 1) * HH, b1s + (k + 1) * H, nullptr, nullptr, nullptr, N);
    } else {
      p3_kernel<1><<<grid, block, 0, stream>>>(
          bufH, acc + (2 * k + 1) * 44, acc + (2 * k + 2) * 44, nullptr,
          g1s + k * H, be1s + k * H, g2s + k * H, be2s + k * H,
          W1s + k * HH, b1s + k * H, W2s + k * HH, b2s + k * H,
          W1s + k * HH, b1s + k * H, Wo, bo, (float*)d_out, N);
    }
  }
}

// Round 6
// 5142.109 us; speedup vs baseline: 8.9681x; 1.4238x over previous
//
#include <hip/hip_runtime.h>

#define H 22
#define HH 484
#define SLOPE 0.01f
#define EPS 1e-5f
#define NBLK 1024
#define NT 256
#define GSZ (NBLK * NT)

// Forbid caching of loop-invariant (weight) loads across row iterations:
// without this, the fully-unrolled matmuls get all weights hoisted into
// registers -> catastrophic spill (rounds 3/4: 2-5 GB scratch traffic).
// Weights re-read each row hit the scalar L1 (s_load, uniform address).
#define ANTI_HOIST() asm volatile("" ::: "memory")

__device__ __forceinline__ float leakyf(float u) { return u > 0.f ? u : SLOPE * u; }

__device__ __forceinline__ void reduce_stats(float red[4][2 * H], const float* s,
                                             const float* q, float* accStage) {
  int lane = threadIdx.x & 63, w = threadIdx.x >> 6;
#pragma unroll
  for (int j = 0; j < H; j++) {
    float a = s[j], b = q[j];
#pragma unroll
    for (int o = 32; o; o >>= 1) { a += __shfl_xor(a, o); b += __shfl_xor(b, o); }
    if (lane == 0) { red[w][j] = a; red[w][H + j] = b; }
  }
  __syncthreads();
  if ((int)threadIdx.x < 2 * H) {
    float v = red[0][threadIdx.x] + red[1][threadIdx.x] +
              red[2][threadIdx.x] + red[3][threadIdx.x];
    atomicAdd(&accStage[threadIdx.x], v);
  }
}

// BN coeffs: sa = g*rsqrt(var+eps), sbf = sa*b + be - sa*mu   (bias-folded)
__device__ __forceinline__ void bn_coef(const float* __restrict__ acc,
                                        const float* __restrict__ g,
                                        const float* __restrict__ be,
                                        const float* __restrict__ b,
                                        float* sa, float* sbf, float invN) {
  int t = threadIdx.x;
  if (t < H) {
    float mu = acc[t] * invN;
    float var = acc[H + t] * invN - mu * mu;
    float a = g[t] * rsqrtf(var + EPS);
    sa[t] = a;
    sbf[t] = a * b[t] + be[t] - a * mu;
  }
}

// ---- proj: z0 = Wp@x + bp -> bufH (feature-major), stats(z0) -> acc stage 0
__global__ void __launch_bounds__(NT) proj_kernel(
    const float* __restrict__ x, const float* __restrict__ Wp,
    const float* __restrict__ bp, float* __restrict__ bufH,
    float* __restrict__ acc0, int N) {
  __shared__ float tile[NT * 65];
  __shared__ float red[4][2 * H];
  int tid = threadIdx.x;

  float s[H], q[H];
#pragma unroll
  for (int j = 0; j < H; j++) { s[j] = 0.f; q[j] = 0.f; }

  const float4* x4 = (const float4*)x;
  for (int it = 0; it < 4; ++it) {  // N / GSZ == 4
    ANTI_HOIST();
    __syncthreads();
    size_t rowbase = (size_t)it * GSZ + (size_t)blockIdx.x * NT;
    size_t base4 = rowbase * 16;
    for (int c = tid; c < NT * 16; c += NT) {
      float4 v = x4[base4 + c];
      float* p = &tile[(c >> 4) * 65 + (c & 15) * 4];
      p[0] = v.x; p[1] = v.y; p[2] = v.z; p[3] = v.w;
    }
    __syncthreads();
    float z[H];
#pragma unroll
    for (int j = 0; j < H; j++) z[j] = bp[j];           // uniform -> s_load
#pragma unroll 1
    for (int dc = 0; dc < 64; dc += 8) {
#pragma unroll
      for (int dd = 0; dd < 8; dd++) {
        float xv = tile[tid * 65 + dc + dd];
#pragma unroll
        for (int j = 0; j < H; j++) z[j] += Wp[j * 64 + dc + dd] * xv;  // s_load
      }
    }
    size_t i = rowbase + tid;
#pragma unroll
    for (int j = 0; j < H; j++) {
      bufH[(size_t)j * N + i] = z[j];
      s[j] += z[j]; q[j] += z[j] * z[j];
    }
  }
  reduce_stats(red, s, q, acc0);
}

// ---- bn0 apply in place + stats of z1_0 (raw W1 h0 + b1)
__global__ void __launch_bounds__(NT) bn0_kernel(
    float* __restrict__ bufH, const float* __restrict__ accIn,
    float* __restrict__ accOut, const float* __restrict__ g0,
    const float* __restrict__ be0, const float* __restrict__ W1,
    const float* __restrict__ b1, int N) {
  __shared__ float sa[H], sc[H];
  __shared__ float red[4][2 * H];
  int tid = threadIdx.x;
  if (tid < H) {
    float invN = 1.0f / (float)N;
    float mu = accIn[tid] * invN;
    float var = accIn[H + tid] * invN - mu * mu;
    float a = g0[tid] * rsqrtf(var + EPS);
    sa[tid] = a; sc[tid] = be0[tid] - a * mu;
  }
  __syncthreads();

  float s[H], q[H];
#pragma unroll
  for (int j = 0; j < H; j++) { s[j] = 0.f; q[j] = 0.f; }

  for (int i = blockIdx.x * NT + tid; i < N; i += GSZ) {
    ANTI_HOIST();
    float h[H];
#pragma unroll
    for (int j = 0; j < H; j++) {
      float v = bufH[(size_t)j * N + i];
      v = sa[j] * v + sc[j];
      bufH[(size_t)j * N + i] = v;
      h[j] = v;
    }
#pragma unroll
    for (int j = 0; j < H; j++) {
      float d = 0.f;
#pragma unroll
      for (int m = 0; m < H; m++) d += W1[j * H + m] * h[m];   // s_load
      float z = d + b1[j];
      s[j] += z; q[j] += z * z;
    }
  }
  reduce_stats(red, s, q, accOut);
}

// ---- P2: t = leaky(a1*dot(W1,h)+b1f) ; z2 = dot(W2,t)+b2 (raw) ; stats(z2)
__global__ void __launch_bounds__(NT) p2_kernel(
    const float* __restrict__ bufH, const float* __restrict__ accIn,
    float* __restrict__ accOut, const float* __restrict__ g1,
    const float* __restrict__ be1, const float* __restrict__ W1,
    const float* __restrict__ b1, const float* __restrict__ W2,
    const float* __restrict__ b2, int N) {
  __shared__ float sa1[H], sb1f[H];
  __shared__ float red[4][2 * H];
  bn_coef(accIn, g1, be1, b1, sa1, sb1f, 1.0f / (float)N);
  __syncthreads();

  float s[H], q[H];
#pragma unroll
  for (int j = 0; j < H; j++) { s[j] = 0.f; q[j] = 0.f; }

  for (int i = blockIdx.x * NT + threadIdx.x; i < N; i += GSZ) {
    ANTI_HOIST();
    float h[H], t[H];
#pragma unroll
    for (int j = 0; j < H; j++) h[j] = bufH[(size_t)j * N + i];
#pragma unroll
    for (int j = 0; j < H; j++) {
      float d = 0.f;
#pragma unroll
      for (int m = 0; m < H; m++) d += W1[j * H + m] * h[m];   // s_load
      t[j] = leakyf(sa1[j] * d + sb1f[j]);
    }
#pragma unroll
    for (int j = 0; j < H; j++) {
      float d = 0.f;
#pragma unroll
      for (int m = 0; m < H; m++) d += W2[j * H + m] * t[m];   // s_load
      float z = d + b2[j];
      s[j] += z; q[j] += z * z;
    }
  }
  reduce_stats(red, s, q, accOut);
}

// ---- P3: recompute t,z2 ; h' = leaky(h + a2*dot(W2,t) + b2f) ; write h' ;
//          fused raw next-layer z1 stats (or final output when LAST)
template <int LAST>
__global__ void __launch_bounds__(NT) p3_kernel(
    float* __restrict__ bufH, const float* __restrict__ accZ1,
    const float* __restrict__ accZ2, float* __restrict__ accOut,
    const float* __restrict__ g1, const float* __restrict__ be1,
    const float* __restrict__ g2, const float* __restrict__ be2,
    const float* __restrict__ W1, const float* __restrict__ b1,
    const float* __restrict__ W2, const float* __restrict__ b2,
    const float* __restrict__ W1n, const float* __restrict__ b1n,
    const float* __restrict__ Wo, const float* __restrict__ bo,
    float* __restrict__ out, int N) {
  __shared__ float sa1[H], sb1f[H], sa2[H], sb2f[H];
  __shared__ float red[4][2 * H];
  float invN = 1.0f / (float)N;
  bn_coef(accZ1, g1, be1, b1, sa1, sb1f, invN);
  bn_coef(accZ2, g2, be2, b2, sa2, sb2f, invN);
  __syncthreads();

  float s[H], q[H];
#pragma unroll
  for (int j = 0; j < H; j++) { s[j] = 0.f; q[j] = 0.f; }

  for (int i = blockIdx.x * NT + threadIdx.x; i < N; i += GSZ) {
    ANTI_HOIST();
    float h[H], t[H];
#pragma unroll
    for (int j = 0; j < H; j++) h[j] = bufH[(size_t)j * N + i];
#pragma unroll
    for (int j = 0; j < H; j++) {
      float d = 0.f;
#pragma unroll
      for (int m = 0; m < H; m++) d += W1[j * H + m] * h[m];   // s_load
      t[j] = leakyf(sa1[j] * d + sb1f[j]);
    }
#pragma unroll
    for (int j = 0; j < H; j++) {
      float d = 0.f;
#pragma unroll
      for (int m = 0; m < H; m++) d += W2[j * H + m] * t[m];   // s_load
      h[j] = leakyf(h[j] + sa2[j] * d + sb2f[j]);
    }
    if (!LAST) {
#pragma unroll
      for (int j = 0; j < H; j++) bufH[(size_t)j * N + i] = h[j];
#pragma unroll
      for (int j = 0; j < H; j++) {
        float d = 0.f;
#pragma unroll
        for (int m = 0; m < H; m++) d += W1n[j * H + m] * h[m];  // s_load
        float z = d + b1n[j];
        s[j] += z; q[j] += z * z;
      }
    } else {
      float o = bo[0];
#pragma unroll
      for (int j = 0; j < H; j++) o += Wo[j] * h[j];             // s_load
      out[i] = o;
    }
  }
  if (!LAST) reduce_stats(red, s, q, accOut);
}

extern "C" void kernel_launch(void* const* d_in, const int* in_sizes, int n_in,
                              void* d_out, int out_size, void* d_ws, size_t ws_size,
                              hipStream_t stream) {
  const float* x    = (const float*)d_in[0];
  const float* Wp   = (const float*)d_in[1];
  const float* bp   = (const float*)d_in[2];
  const float* g0   = (const float*)d_in[3];
  const float* be0  = (const float*)d_in[4];
  const float* W1s  = (const float*)d_in[5];
  const float* b1s  = (const float*)d_in[6];
  const float* g1s  = (const float*)d_in[7];
  const float* be1s = (const float*)d_in[8];
  const float* W2s  = (const float*)d_in[9];
  const float* b2s  = (const float*)d_in[10];
  const float* g2s  = (const float*)d_in[11];
  const float* be2s = (const float*)d_in[12];
  const float* Wo   = (const float*)d_in[13];
  const float* bo   = (const float*)d_in[14];

  int N = in_sizes[0] / 64;  // 1048576

  float* bufH = (float*)d_ws;
  float* acc = bufH + (size_t)H * N;  // 33 stages x 44 floats

  hipMemsetAsync(acc, 0, 33 * 2 * H * sizeof(float), stream);

  dim3 grid(NBLK), block(NT);

  proj_kernel<<<grid, block, 0, stream>>>(x, Wp, bp, bufH, acc, N);
  bn0_kernel<<<grid, block, 0, stream>>>(bufH, acc, acc + 44, g0, be0, W1s, b1s, N);

  for (int k = 0; k < 16; k++) {
    p2_kernel<<<grid, block, 0, stream>>>(
        bufH, acc + (2 * k + 1) * 44, acc + (2 * k + 2) * 44,
        g1s + k * H, be1s + k * H, W1s + k * HH, b1s + k * H,
        W2s + k * HH, b2s + k * H, N);
    if (k < 15) {
      p3_kernel<0><<<grid, block, 0, stream>>>(
          bufH, acc + (2 * k + 1) * 44, acc + (2 * k + 2) * 44, acc + (2 * k + 3) * 44,
          g1s + k * H, be1s + k * H, g2s + k * H, be2s + k * H,
          W1s + k * HH, b1s + k * H, W2s + k * HH, b2s + k * H,
          W1s + (k + 1) * HH, b1s + (k + 1) * H, nullptr, nullptr, nullptr, N);
    } else {
      p3_kernel<1><<<grid, block, 0, stream>>>(
          bufH, acc + (2 * k + 1) * 44, acc + (2 * k + 2) * 44, nullptr,
          g1s + k * H, be1s + k * H, g2s + k * H, be2s + k * H,
          W1s + k * HH, b1s + k * H, W2s + k * HH, b2s + k * H,
          W1s + k * HH, b1s + k * H, Wo, bo, (float*)d_out, N);
    }
  }
}

// Round 7
// 4710.200 us; speedup vs baseline: 9.7904x; 1.0917x over previous
//
#include <hip/hip_runtime.h>

#define H 22
#define HH 484
#define SLOPE 0.01f
#define EPS 1e-5f
#define NBLK 1024
#define NT 256
#define GSZ (NBLK * NT)

// Forbid caching of loop-invariant (weight) loads across row iterations:
// without this, the fully-unrolled matmuls get all weights hoisted into
// registers -> catastrophic spill (rounds 3/4: 2-5 GB scratch traffic).
// Weights re-read each iteration hit the scalar L1 (s_load, uniform address).
#define ANTI_HOIST() asm volatile("" ::: "memory")

__device__ __forceinline__ float leakyf(float u) { return u > 0.f ? u : SLOPE * u; }

__device__ __forceinline__ void reduce_stats(float red[4][2 * H], const float* s,
                                             const float* q, float* accStage) {
  int lane = threadIdx.x & 63, w = threadIdx.x >> 6;
#pragma unroll
  for (int j = 0; j < H; j++) {
    float a = s[j], b = q[j];
#pragma unroll
    for (int o = 32; o; o >>= 1) { a += __shfl_xor(a, o); b += __shfl_xor(b, o); }
    if (lane == 0) { red[w][j] = a; red[w][H + j] = b; }
  }
  __syncthreads();
  if ((int)threadIdx.x < 2 * H) {
    float v = red[0][threadIdx.x] + red[1][threadIdx.x] +
              red[2][threadIdx.x] + red[3][threadIdx.x];
    atomicAdd(&accStage[threadIdx.x], v);
  }
}

// BN coeffs: sa = g*rsqrt(var+eps), sbf = sa*b + be - sa*mu   (bias-folded)
__device__ __forceinline__ void bn_coef(const float* __restrict__ acc,
                                        const float* __restrict__ g,
                                        const float* __restrict__ be,
                                        const float* __restrict__ b,
                                        float* sa, float* sbf, float invN) {
  int t = threadIdx.x;
  if (t < H) {
    float mu = acc[t] * invN;
    float var = acc[H + t] * invN - mu * mu;
    float a = g[t] * rsqrtf(var + EPS);
    sa[t] = a;
    sbf[t] = a * b[t] + be[t] - a * mu;
  }
}

// ---- proj: z0 = Wp@x + bp -> bufH (feature-major), stats(z0) -> acc stage 0
__global__ void __launch_bounds__(NT) proj_kernel(
    const float* __restrict__ x, const float* __restrict__ Wp,
    const float* __restrict__ bp, float* __restrict__ bufH,
    float* __restrict__ acc0, int N) {
  __shared__ float tile[NT * 65];
  __shared__ float red[4][2 * H];
  int tid = threadIdx.x;

  float s[H], q[H];
#pragma unroll
  for (int j = 0; j < H; j++) { s[j] = 0.f; q[j] = 0.f; }

  const float4* x4 = (const float4*)x;
  for (int it = 0; it < 4; ++it) {  // N / GSZ == 4
    ANTI_HOIST();
    __syncthreads();
    size_t rowbase = (size_t)it * GSZ + (size_t)blockIdx.x * NT;
    size_t base4 = rowbase * 16;
    for (int c = tid; c < NT * 16; c += NT) {
      float4 v = x4[base4 + c];
      float* p = &tile[(c >> 4) * 65 + (c & 15) * 4];
      p[0] = v.x; p[1] = v.y; p[2] = v.z; p[3] = v.w;
    }
    __syncthreads();
    float z[H];
#pragma unroll
    for (int j = 0; j < H; j++) z[j] = bp[j];           // uniform -> s_load
#pragma unroll 1
    for (int dc = 0; dc < 64; dc += 8) {
#pragma unroll
      for (int dd = 0; dd < 8; dd++) {
        float xv = tile[tid * 65 + dc + dd];
#pragma unroll
        for (int j = 0; j < H; j++) z[j] += Wp[j * 64 + dc + dd] * xv;  // s_load
      }
    }
    size_t i = rowbase + tid;
#pragma unroll
    for (int j = 0; j < H; j++) {
      bufH[(size_t)j * N + i] = z[j];
      s[j] += z[j]; q[j] += z[j] * z[j];
    }
  }
  reduce_stats(red, s, q, acc0);
}

// ---- bn0: apply bn in place (2 rows/thread) + stats of z1_0 = W1 h0 + b1
__global__ void __launch_bounds__(NT) bn0_kernel(
    float* __restrict__ bufH, const float* __restrict__ accIn,
    float* __restrict__ accOut, const float* __restrict__ g0,
    const float* __restrict__ be0, const float* __restrict__ W1,
    const float* __restrict__ b1, int N) {
  __shared__ float sa[H], sc[H];
  __shared__ float red[4][2 * H];
  int tid = threadIdx.x;
  if (tid < H) {
    float invN = 1.0f / (float)N;
    float mu = accIn[tid] * invN;
    float var = accIn[H + tid] * invN - mu * mu;
    float a = g0[tid] * rsqrtf(var + EPS);
    sa[tid] = a; sc[tid] = be0[tid] - a * mu;
  }
  __syncthreads();

  float s[H], q[H];
#pragma unroll
  for (int j = 0; j < H; j++) { s[j] = 0.f; q[j] = 0.f; }

  float2* bufH2 = (float2*)bufH;
  int NP = N >> 1;
  for (int p = blockIdx.x * NT + tid; p < NP; p += GSZ) {
    ANTI_HOIST();
    float2 h[H];
#pragma unroll
    for (int j = 0; j < H; j++) {
      float2 v = bufH2[(size_t)j * NP + p];
      v.x = sa[j] * v.x + sc[j];
      v.y = sa[j] * v.y + sc[j];
      bufH2[(size_t)j * NP + p] = v;
      h[j] = v;
    }
#pragma unroll
    for (int j = 0; j < H; j++) {
      float dx = 0.f, dy = 0.f;
#pragma unroll
      for (int m = 0; m < H; m++) {
        float w = W1[j * H + m];                         // s_load, reused x2
        dx += w * h[m].x; dy += w * h[m].y;
      }
      float zx = dx + b1[j], zy = dy + b1[j];
      s[j] += zx + zy; q[j] += zx * zx + zy * zy;
    }
  }
  reduce_stats(red, s, q, accOut);
}

// ---- P2 (2 rows/thread): t = leaky(a1*dot(W1,h)+b1f) ; z2 = dot(W2,t)+b2 ; stats(z2)
__global__ void __launch_bounds__(NT) p2_kernel(
    const float* __restrict__ bufH, const float* __restrict__ accIn,
    float* __restrict__ accOut, const float* __restrict__ g1,
    const float* __restrict__ be1, const float* __restrict__ W1,
    const float* __restrict__ b1, const float* __restrict__ W2,
    const float* __restrict__ b2, int N) {
  __shared__ float sa1[H], sb1f[H];
  __shared__ float red[4][2 * H];
  bn_coef(accIn, g1, be1, b1, sa1, sb1f, 1.0f / (float)N);
  __syncthreads();

  float s[H], q[H];
#pragma unroll
  for (int j = 0; j < H; j++) { s[j] = 0.f; q[j] = 0.f; }

  const float2* bufH2 = (const float2*)bufH;
  int NP = N >> 1;
  for (int p = blockIdx.x * NT + threadIdx.x; p < NP; p += GSZ) {
    ANTI_HOIST();
    float2 h[H], t[H];
#pragma unroll
    for (int j = 0; j < H; j++) h[j] = bufH2[(size_t)j * NP + p];
#pragma unroll
    for (int j = 0; j < H; j++) {
      float dx = 0.f, dy = 0.f;
#pragma unroll
      for (int m = 0; m < H; m++) {
        float w = W1[j * H + m];                         // s_load, reused x2
        dx += w * h[m].x; dy += w * h[m].y;
      }
      t[j].x = leakyf(sa1[j] * dx + sb1f[j]);
      t[j].y = leakyf(sa1[j] * dy + sb1f[j]);
    }
#pragma unroll
    for (int j = 0; j < H; j++) {
      float dx = 0.f, dy = 0.f;
#pragma unroll
      for (int m = 0; m < H; m++) {
        float w = W2[j * H + m];                         // s_load, reused x2
        dx += w * t[m].x; dy += w * t[m].y;
      }
      float zx = dx + b2[j], zy = dy + b2[j];
      s[j] += zx + zy; q[j] += zx * zx + zy * zy;
    }
  }
  reduce_stats(red, s, q, accOut);
}

// ---- P3 (2 rows/thread): recompute t,z2 ; h' = leaky(h + a2*dot(W2,t)+b2f) ;
//      write h' ; fused raw next-layer z1 stats (or final output when LAST)
template <int LAST>
__global__ void __launch_bounds__(NT) p3_kernel(
    float* __restrict__ bufH, const float* __restrict__ accZ1,
    const float* __restrict__ accZ2, float* __restrict__ accOut,
    const float* __restrict__ g1, const float* __restrict__ be1,
    const float* __restrict__ g2, const float* __restrict__ be2,
    const float* __restrict__ W1, const float* __restrict__ b1,
    const float* __restrict__ W2, const float* __restrict__ b2,
    const float* __restrict__ W1n, const float* __restrict__ b1n,
    const float* __restrict__ Wo, const float* __restrict__ bo,
    float* __restrict__ out, int N) {
  __shared__ float sa1[H], sb1f[H], sa2[H], sb2f[H];
  __shared__ float red[4][2 * H];
  float invN = 1.0f / (float)N;
  bn_coef(accZ1, g1, be1, b1, sa1, sb1f, invN);
  bn_coef(accZ2, g2, be2, b2, sa2, sb2f, invN);
  __syncthreads();

  float s[H], q[H];
#pragma unroll
  for (int j = 0; j < H; j++) { s[j] = 0.f; q[j] = 0.f; }

  float2* bufH2 = (float2*)bufH;
  int NP = N >> 1;
  for (int p = blockIdx.x * NT + threadIdx.x; p < NP; p += GSZ) {
    ANTI_HOIST();
    float2 h[H], t[H];
#pragma unroll
    for (int j = 0; j < H; j++) h[j] = bufH2[(size_t)j * NP + p];
#pragma unroll
    for (int j = 0; j < H; j++) {
      float dx = 0.f, dy = 0.f;
#pragma unroll
      for (int m = 0; m < H; m++) {
        float w = W1[j * H + m];                         // s_load, reused x2
        dx += w * h[m].x; dy += w * h[m].y;
      }
      t[j].x = leakyf(sa1[j] * dx + sb1f[j]);
      t[j].y = leakyf(sa1[j] * dy + sb1f[j]);
    }
#pragma unroll
    for (int j = 0; j < H; j++) {
      float dx = 0.f, dy = 0.f;
#pragma unroll
      for (int m = 0; m < H; m++) {
        float w = W2[j * H + m];                         // s_load, reused x2
        dx += w * t[m].x; dy += w * t[m].y;
      }
      h[j].x = leakyf(h[j].x + sa2[j] * dx + sb2f[j]);
      h[j].y = leakyf(h[j].y + sa2[j] * dy + sb2f[j]);
    }
    if (!LAST) {
#pragma unroll
      for (int j = 0; j < H; j++) bufH2[(size_t)j * NP + p] = h[j];
#pragma unroll
      for (int j = 0; j < H; j++) {
        float dx = 0.f, dy = 0.f;
#pragma unroll
        for (int m = 0; m < H; m++) {
          float w = W1n[j * H + m];                      // s_load, reused x2
          dx += w * h[m].x; dy += w * h[m].y;
        }
        float zx = dx + b1n[j], zy = dy + b1n[j];
        s[j] += zx + zy; q[j] += zx * zx + zy * zy;
      }
    } else {
      float ox = bo[0], oy = bo[0];
#pragma unroll
      for (int j = 0; j < H; j++) {
        float w = Wo[j];                                 // s_load
        ox += w * h[j].x; oy += w * h[j].y;
      }
      ((float2*)out)[p] = make_float2(ox, oy);
    }
  }
  if (!LAST) reduce_stats(red, s, q, accOut);
}

extern "C" void kernel_launch(void* const* d_in, const int* in_sizes, int n_in,
                              void* d_out, int out_size, void* d_ws, size_t ws_size,
                              hipStream_t stream) {
  const float* x    = (const float*)d_in[0];
  const float* Wp   = (const float*)d_in[1];
  const float* bp   = (const float*)d_in[2];
  const float* g0   = (const float*)d_in[3];
  const float* be0  = (const float*)d_in[4];
  const float* W1s  = (const float*)d_in[5];
  const float* b1s  = (const float*)d_in[6];
  const float* g1s  = (const float*)d_in[7];
  const float* be1s = (const float*)d_in[8];
  const float* W2s  = (const float*)d_in[9];
  const float* b2s  = (const float*)d_in[10];
  const float* g2s  = (const float*)d_in[11];
  const float* be2s = (const float*)d_in[12];
  const float* Wo   = (const float*)d_in[13];
  const float* bo   = (const float*)d_in[14];

  int N = in_sizes[0] / 64;  // 1048576

  float* bufH = (float*)d_ws;
  float* acc = bufH + (size_t)H * N;  // 33 stages x 44 floats

  hipMemsetAsync(acc, 0, 33 * 2 * H * sizeof(float), stream);

  dim3 grid(NBLK), block(NT);

  proj_kernel<<<grid, block, 0, stream>>>(x, Wp, bp, bufH, acc, N);
  bn0_kernel<<<grid, block, 0, stream>>>(bufH, acc, acc + 44, g0, be0, W1s, b1s, N);

  for (int k = 0; k < 16; k++) {
    p2_kernel<<<grid, block, 0, stream>>>(
        bufH, acc + (2 * k + 1) * 44, acc + (2 * k + 2) * 44,
        g1s + k * H, be1s + k * H, W1s + k * HH, b1s + k * H,
        W2s + k * HH, b2s + k * H, N);
    if (k < 15) {
      p3_kernel<0><<<grid, block, 0, stream>>>(
          bufH, acc + (2 * k + 1) * 44, acc + (2 * k + 2) * 44, acc + (2 * k + 3) * 44,
          g1s + k * H, be1s + k * H, g2s + k * H, be2s + k * H,
          W1s + k * HH, b1s + k * H, W2s + k * HH, b2s + k * H,
          W1s + (k + 1) * HH, b1s + (k + 1) * H, nullptr, nullptr, nullptr, N);
    } else {
      p3_kernel<1><<<grid, block, 0, stream>>>(
          bufH, acc + (2 * k + 1) * 44, acc + (2 * k + 2) * 44, nullptr,
          g1s + k * H, be1s + k * H, g2s + k * H, be2s + k * H,
          W1s + k * HH, b1s + k * H, W2s + k * HH, b2s + k * H,
          W1s + k * HH, b1s + k * H, Wo, bo, (float*)d_out, N);
    }
  }
}

// Round 8
// 1188.358 us; speedup vs baseline: 38.8055x; 3.9636x over previous
//
#include <hip/hip_runtime.h>

#define H 22
#define EPS 1e-5f
#define SLOPE 0.01f
#define NT 256
#define NBLK 1024
#define WPB 4
#define NWAVES (NBLK * WPB)

typedef __attribute__((ext_vector_type(8))) _Float16 half8;
typedef __attribute__((ext_vector_type(4))) float f32x4;

#define MFMA(A, B, C) __builtin_amdgcn_mfma_f32_16x16x32_f16(A, B, C, 0, 0, 0)

__device__ __forceinline__ float leakyf(float u) { return u > 0.f ? u : SLOPE * u; }

// k/m mapping used CONSISTENTLY for all operand constructions:
// k(g,e) = 16*(e>>2) + 4*g + (e&3).  C-frag m at (tile,reg) = kmap(g, 4*tile+reg),
// so chained C->B repack is in-lane. Any deviation from the true HW k-map applies
// the same permutation to A and B and cancels in the contraction.
__device__ __forceinline__ int kmap(int g, int e) {
  return ((e >> 2) << 4) + (g << 2) + (e & 3);
}

// Build A-fragment of W (rows x cols row-major), M-tile at mbase, K-offset kbase.
// Out-of-range (m>=rows or k>=cols) -> 0 (handles 22->32 padding).
__device__ __forceinline__ half8 buildA(const float* __restrict__ W, int rows, int cols,
                                        int mbase, int kbase, int g) {
  int m = mbase + ((int)threadIdx.x & 15);
  half8 a;
#pragma unroll
  for (int e = 0; e < 8; e++) {
    int k = kbase + kmap(g, e);
    float v = (m < rows && k < cols) ? W[m * cols + k] : 0.f;
    a[e] = (_Float16)v;
  }
  return a;
}

// per-wave stats (s,q indexed by e: feature m = kmap(g,e)) -> block reduce -> atomics
__device__ __forceinline__ void commit_stats(float* s, float* q,
                                             float red[WPB][2 * H],
                                             float* __restrict__ accOut) {
  int lane = (int)threadIdx.x & 63, w = (int)threadIdx.x >> 6, g = lane >> 4;
#pragma unroll
  for (int r = 0; r < 8; r++) {
#pragma unroll
    for (int off = 1; off < 16; off <<= 1) {
      s[r] += __shfl_xor(s[r], off);
      q[r] += __shfl_xor(q[r], off);
    }
  }
  if ((lane & 15) == 0) {
#pragma unroll
    for (int r = 0; r < 8; r++) {
      int m = kmap(g, r);
      if (m < H) { red[w][m] = s[r]; red[w][H + m] = q[r]; }
    }
  }
  __syncthreads();
  if ((int)threadIdx.x < 2 * H) {
    float v = red[0][threadIdx.x] + red[1][threadIdx.x] +
              red[2][threadIdx.x] + red[3][threadIdx.x];
    atomicAdd(&accOut[threadIdx.x], v);
  }
}

// ---- proj: z0 = Wp @ x + bp -> bufT (f16 frag layout), stats(z0) -> acc stage 0
__global__ void __launch_bounds__(NT) proj_kernel(
    const float* __restrict__ x, const float* __restrict__ Wp,
    const float* __restrict__ bp, half8* __restrict__ bufT,
    float* __restrict__ acc0, int ntiles) {
  __shared__ float sBP[32];
  __shared__ float red[WPB][2 * H];
  int tid = threadIdx.x;
  if (tid < 32) sBP[tid] = (tid < H) ? bp[tid] : 0.f;
  __syncthreads();
  int lane = tid & 63, w = tid >> 6, g = lane >> 4, n = lane & 15;
  int wid = blockIdx.x * WPB + w;

  half8 A00 = buildA(Wp, H, 64, 0, 0, g);
  half8 A01 = buildA(Wp, H, 64, 0, 32, g);
  half8 A10 = buildA(Wp, H, 64, 16, 0, g);
  half8 A11 = buildA(Wp, H, 64, 16, 32, g);
  float bpv[8];
#pragma unroll
  for (int e = 0; e < 8; e++) bpv[e] = sBP[kmap(g, e)];

  float s[8], q[8];
#pragma unroll
  for (int e = 0; e < 8; e++) { s[e] = 0.f; q[e] = 0.f; }

  const float4* x4 = (const float4*)x;
  for (int t = wid; t < ntiles; t += NWAVES) {
    size_t row = (size_t)t * 16 + n;
    float4 lo0 = x4[row * 16 + g];        // k = 4g..4g+3
    float4 hi0 = x4[row * 16 + 4 + g];    // k = 16+4g..
    float4 lo1 = x4[row * 16 + 8 + g];    // k = 32+4g..
    float4 hi1 = x4[row * 16 + 12 + g];   // k = 48+4g..
    half8 B0, B1;
    B0[0] = (_Float16)lo0.x; B0[1] = (_Float16)lo0.y;
    B0[2] = (_Float16)lo0.z; B0[3] = (_Float16)lo0.w;
    B0[4] = (_Float16)hi0.x; B0[5] = (_Float16)hi0.y;
    B0[6] = (_Float16)hi0.z; B0[7] = (_Float16)hi0.w;
    B1[0] = (_Float16)lo1.x; B1[1] = (_Float16)lo1.y;
    B1[2] = (_Float16)lo1.z; B1[3] = (_Float16)lo1.w;
    B1[4] = (_Float16)hi1.x; B1[5] = (_Float16)hi1.y;
    B1[6] = (_Float16)hi1.z; B1[7] = (_Float16)hi1.w;

    f32x4 c0 = {0.f, 0.f, 0.f, 0.f}, c1 = {0.f, 0.f, 0.f, 0.f};
    c0 = MFMA(A00, B0, c0); c0 = MFMA(A01, B1, c0);
    c1 = MFMA(A10, B0, c1); c1 = MFMA(A11, B1, c1);

    half8 zb;
#pragma unroll
    for (int e = 0; e < 8; e++) {
      float z = ((e < 4) ? c0[e & 3] : c1[e & 3]) + bpv[e];  // m>=22: A rows 0, bpv 0 -> z=0
      s[e] += z; q[e] += z * z;
      zb[e] = (_Float16)z;
    }
    bufT[(size_t)t * 64 + g * 16 + n] = zb;
  }
  commit_stats(s, q, red, acc0);
}

// ---- bn0: h0 = a0*z0 + c0 (in place) ; stats of z1_0 = W1 h0 + b1
__global__ void __launch_bounds__(NT) bn0_kernel(
    half8* __restrict__ bufT, const float* __restrict__ accIn,
    float* __restrict__ accOut, const float* __restrict__ g0,
    const float* __restrict__ be0, const float* __restrict__ W1,
    const float* __restrict__ b1, int ntiles, float invN) {
  __shared__ float sA[32], sC[32], sB1[32];
  __shared__ float red[WPB][2 * H];
  int tid = threadIdx.x;
  if (tid < 32) {
    float a = 0.f, c = 0.f, bv = 0.f;
    if (tid < H) {
      float mu = accIn[tid] * invN;
      float var = accIn[H + tid] * invN - mu * mu;
      a = g0[tid] * rsqrtf(var + EPS);
      c = be0[tid] - a * mu;
      bv = b1[tid];
    }
    sA[tid] = a; sC[tid] = c; sB1[tid] = bv;
  }
  __syncthreads();
  int lane = tid & 63, w = tid >> 6, g = lane >> 4, n = lane & 15;
  int wid = blockIdx.x * WPB + w;

  half8 A0 = buildA(W1, H, H, 0, 0, g), A1 = buildA(W1, H, H, 16, 0, g);
  float aK[8], cK[8], b1v[8];
#pragma unroll
  for (int e = 0; e < 8; e++) {
    int m = kmap(g, e);
    aK[e] = sA[m]; cK[e] = sC[m]; b1v[e] = sB1[m];
  }
  float s[8], q[8];
#pragma unroll
  for (int e = 0; e < 8; e++) { s[e] = 0.f; q[e] = 0.f; }

  for (int t = wid; t < ntiles; t += NWAVES) {
    size_t idx = (size_t)t * 64 + g * 16 + n;
    half8 zb = bufT[idx];
    half8 hb;
#pragma unroll
    for (int e = 0; e < 8; e++)
      hb[e] = (_Float16)(aK[e] * (float)zb[e] + cK[e]);   // pad features: aK=cK=0 -> 0
    bufT[idx] = hb;
    f32x4 c0 = {0.f, 0.f, 0.f, 0.f}, c1 = {0.f, 0.f, 0.f, 0.f};
    c0 = MFMA(A0, hb, c0);
    c1 = MFMA(A1, hb, c1);
#pragma unroll
    for (int e = 0; e < 8; e++) {
      float z = ((e < 4) ? c0[e & 3] : c1[e & 3]) + b1v[e];
      s[e] += z; q[e] += z * z;
    }
  }
  commit_stats(s, q, red, accOut);
}

// ---- P2: t = leaky(a1*(W1 h) + b1f) ; z2 = W2 t + b2 (raw) ; stats(z2)
__global__ void __launch_bounds__(NT) p2_kernel(
    const half8* __restrict__ bufT, const float* __restrict__ accIn,
    float* __restrict__ accOut, const float* __restrict__ g1,
    const float* __restrict__ be1, const float* __restrict__ W1,
    const float* __restrict__ b1, const float* __restrict__ W2,
    const float* __restrict__ b2, int ntiles, float invN) {
  __shared__ float sA1[32], sB1F[32], sB2[32];
  __shared__ float red[WPB][2 * H];
  int tid = threadIdx.x;
  if (tid < 32) {
    float a = 0.f, bf = 0.f, bv = 0.f;
    if (tid < H) {
      float mu = accIn[tid] * invN;
      float var = accIn[H + tid] * invN - mu * mu;
      a = g1[tid] * rsqrtf(var + EPS);
      bf = a * b1[tid] + be1[tid] - a * mu;
      bv = b2[tid];
    }
    sA1[tid] = a; sB1F[tid] = bf; sB2[tid] = bv;
  }
  __syncthreads();
  int lane = tid & 63, w = tid >> 6, g = lane >> 4, n = lane & 15;
  int wid = blockIdx.x * WPB + w;

  half8 A10 = buildA(W1, H, H, 0, 0, g), A11 = buildA(W1, H, H, 16, 0, g);
  half8 A20 = buildA(W2, H, H, 0, 0, g), A21 = buildA(W2, H, H, 16, 0, g);
  float a1v[8], b1v[8], b2v[8];
#pragma unroll
  for (int e = 0; e < 8; e++) {
    int m = kmap(g, e);
    a1v[e] = sA1[m]; b1v[e] = sB1F[m]; b2v[e] = sB2[m];
  }
  float s[8], q[8];
#pragma unroll
  for (int e = 0; e < 8; e++) { s[e] = 0.f; q[e] = 0.f; }

  for (int t = wid; t < ntiles; t += NWAVES) {
    half8 hb = bufT[(size_t)t * 64 + g * 16 + n];
    f32x4 c0 = {0.f, 0.f, 0.f, 0.f}, c1 = {0.f, 0.f, 0.f, 0.f};
    c0 = MFMA(A10, hb, c0);
    c1 = MFMA(A11, hb, c1);
    half8 tb;
#pragma unroll
    for (int e = 0; e < 8; e++) {
      float c = (e < 4) ? c0[e & 3] : c1[e & 3];
      tb[e] = (_Float16)leakyf(a1v[e] * c + b1v[e]);      // pad: a1v=b1v=0 -> 0
    }
    f32x4 d0 = {0.f, 0.f, 0.f, 0.f}, d1 = {0.f, 0.f, 0.f, 0.f};
    d0 = MFMA(A20, tb, d0);
    d1 = MFMA(A21, tb, d1);
#pragma unroll
    for (int e = 0; e < 8; e++) {
      float z = ((e < 4) ? d0[e & 3] : d1[e & 3]) + b2v[e];
      s[e] += z; q[e] += z * z;
    }
  }
  commit_stats(s, q, red, accOut);
}

// ---- P3: recompute t, z2 ; h' = leaky(h + a2*(W2 t) + b2f) ; store h' ;
//          fused next-layer z1 stats (raw) or final output when LAST
template <int LAST>
__global__ void __launch_bounds__(NT) p3_kernel(
    half8* __restrict__ bufT, const float* __restrict__ accZ1,
    const float* __restrict__ accZ2, float* __restrict__ accOut,
    const float* __restrict__ g1, const float* __restrict__ be1,
    const float* __restrict__ g2, const float* __restrict__ be2,
    const float* __restrict__ W1, const float* __restrict__ b1,
    const float* __restrict__ W2, const float* __restrict__ b2,
    const float* __restrict__ W1n, const float* __restrict__ b1n,
    const float* __restrict__ Wo, const float* __restrict__ bo,
    float* __restrict__ out, int ntiles, float invN) {
  __shared__ float sA1[32], sB1F[32], sA2[32], sB2F[32], sAux[32];
  __shared__ float red[WPB][2 * H];
  int tid = threadIdx.x;
  if (tid < 32) {
    float a1 = 0.f, b1f = 0.f, a2 = 0.f, b2f = 0.f, aux = 0.f;
    if (tid < H) {
      float mu1 = accZ1[tid] * invN;
      float v1 = accZ1[H + tid] * invN - mu1 * mu1;
      a1 = g1[tid] * rsqrtf(v1 + EPS);
      b1f = a1 * b1[tid] + be1[tid] - a1 * mu1;
      float mu2 = accZ2[tid] * invN;
      float v2 = accZ2[H + tid] * invN - mu2 * mu2;
      a2 = g2[tid] * rsqrtf(v2 + EPS);
      b2f = a2 * b2[tid] + be2[tid] - a2 * mu2;
      aux = LAST ? Wo[tid] : b1n[tid];
    }
    sA1[tid] = a1; sB1F[tid] = b1f; sA2[tid] = a2; sB2F[tid] = b2f; sAux[tid] = aux;
  }
  __syncthreads();
  int lane = tid & 63, w = tid >> 6, g = lane >> 4, n = lane & 15;
  int wid = blockIdx.x * WPB + w;

  half8 A10 = buildA(W1, H, H, 0, 0, g), A11 = buildA(W1, H, H, 16, 0, g);
  half8 A20 = buildA(W2, H, H, 0, 0, g), A21 = buildA(W2, H, H, 16, 0, g);
  half8 An0, An1;
  if (!LAST) { An0 = buildA(W1n, H, H, 0, 0, g); An1 = buildA(W1n, H, H, 16, 0, g); }
  float a1v[8], b1v[8], a2v[8], b2v[8], auxv[8];
#pragma unroll
  for (int e = 0; e < 8; e++) {
    int m = kmap(g, e);
    a1v[e] = sA1[m]; b1v[e] = sB1F[m]; a2v[e] = sA2[m]; b2v[e] = sB2F[m]; auxv[e] = sAux[m];
  }
  float s[8], q[8];
#pragma unroll
  for (int e = 0; e < 8; e++) { s[e] = 0.f; q[e] = 0.f; }
  float bo0 = LAST ? bo[0] : 0.f;

  for (int t = wid; t < ntiles; t += NWAVES) {
    size_t idx = (size_t)t * 64 + g * 16 + n;
    half8 hb = bufT[idx];
    f32x4 c0 = {0.f, 0.f, 0.f, 0.f}, c1 = {0.f, 0.f, 0.f, 0.f};
    c0 = MFMA(A10, hb, c0);
    c1 = MFMA(A11, hb, c1);
    half8 tb;
#pragma unroll
    for (int e = 0; e < 8; e++) {
      float c = (e < 4) ? c0[e & 3] : c1[e & 3];
      tb[e] = (_Float16)leakyf(a1v[e] * c + b1v[e]);
    }
    f32x4 d0 = {0.f, 0.f, 0.f, 0.f}, d1 = {0.f, 0.f, 0.f, 0.f};
    d0 = MFMA(A20, tb, d0);
    d1 = MFMA(A21, tb, d1);
    float hn[8];
    half8 nb;
#pragma unroll
    for (int e = 0; e < 8; e++) {
      float d = (e < 4) ? d0[e & 3] : d1[e & 3];
      // residual: C-frag m at (tile,reg)=e equals B-elem feature kmap(g,e) -> same lane/elem
      float hv = (float)hb[e];
      hn[e] = leakyf(hv + a2v[e] * d + b2v[e]);            // pad: a2v=b2v=0, hv=0 -> 0
      nb[e] = (_Float16)hn[e];
    }
    if (!LAST) {
      bufT[idx] = nb;
      f32x4 e0 = {0.f, 0.f, 0.f, 0.f}, e1 = {0.f, 0.f, 0.f, 0.f};
      e0 = MFMA(An0, nb, e0);
      e1 = MFMA(An1, nb, e1);
#pragma unroll
      for (int e = 0; e < 8; e++) {
        float z = ((e < 4) ? e0[e & 3] : e1[e & 3]) + auxv[e];
        s[e] += z; q[e] += z * z;
      }
    } else {
      float part = 0.f;
#pragma unroll
      for (int e = 0; e < 8; e++) part += auxv[e] * hn[e];
      part += __shfl_xor(part, 16);
      part += __shfl_xor(part, 32);
      if (lane < 16) out[(size_t)t * 16 + n] = part + bo0;
    }
  }
  if (!LAST) commit_stats(s, q, red, accOut);
}

extern "C" void kernel_launch(void* const* d_in, const int* in_sizes, int n_in,
                              void* d_out, int out_size, void* d_ws, size_t ws_size,
                              hipStream_t stream) {
  const float* x    = (const float*)d_in[0];
  const float* Wp   = (const float*)d_in[1];
  const float* bp   = (const float*)d_in[2];
  const float* g0   = (const float*)d_in[3];
  const float* be0  = (const float*)d_in[4];
  const float* W1s  = (const float*)d_in[5];
  const float* b1s  = (const float*)d_in[6];
  const float* g1s  = (const float*)d_in[7];
  const float* be1s = (const float*)d_in[8];
  const float* W2s  = (const float*)d_in[9];
  const float* b2s  = (const float*)d_in[10];
  const float* g2s  = (const float*)d_in[11];
  const float* be2s = (const float*)d_in[12];
  const float* Wo   = (const float*)d_in[13];
  const float* bo   = (const float*)d_in[14];

  int N = in_sizes[0] / 64;  // 1048576
  int ntiles = N / 16;       // 65536
  float invN = 1.0f / (float)N;

  half8* bufT = (half8*)d_ws;                         // 64 MB f16 fragment buffer
  float* acc = (float*)(bufT + (size_t)ntiles * 64);  // 33 stages x 44 floats

  hipMemsetAsync(acc, 0, 33 * 2 * H * sizeof(float), stream);

  dim3 grid(NBLK), block(NT);
  const int HH = H * H;

  proj_kernel<<<grid, block, 0, stream>>>(x, Wp, bp, bufT, acc, ntiles);
  bn0_kernel<<<grid, block, 0, stream>>>(bufT, acc, acc + 44, g0, be0, W1s, b1s,
                                         ntiles, invN);

  for (int k = 0; k < 16; k++) {
    p2_kernel<<<grid, block, 0, stream>>>(
        bufT, acc + (2 * k + 1) * 44, acc + (2 * k + 2) * 44,
        g1s + k * H, be1s + k * H, W1s + k * HH, b1s + k * H,
        W2s + k * HH, b2s + k * H, ntiles, invN);
    if (k < 15) {
      p3_kernel<0><<<grid, block, 0, stream>>>(
          bufT, acc + (2 * k + 1) * 44, acc + (2 * k + 2) * 44, acc + (2 * k + 3) * 44,
          g1s + k * H, be1s + k * H, g2s + k * H, be2s + k * H,
          W1s + k * HH, b1s + k * H, W2s + k * HH, b2s + k * H,
          W1s + (k + 1) * HH, b1s + (k + 1) * H, nullptr, nullptr, nullptr,
          ntiles, invN);
    } else {
      p3_kernel<1><<<grid, block, 0, stream>>>(
          bufT, acc + (2 * k + 1) * 44, acc + (2 * k + 2) * 44, nullptr,
          g1s + k * H, be1s + k * H, g2s + k * H, be2s + k * H,
          W1s + k * HH, b1s + k * H, W2s + k * HH, b2s + k * H,
          W1s + k * HH, b1s + k * H, Wo, bo, (float*)d_out, ntiles, invN);
    }
  }
}